// Round 6
// baseline (1141.337 us; speedup 1.0000x reference)
//
#include <hip/hip_runtime.h>
#include <math.h>

#define B_ 16
#define N_ 4096
#define G_ 1024
#define D_ 256
#define DT_ 0.01f
#define EPS_ 1e-5f

typedef float f32x4 __attribute__((ext_vector_type(4)));
typedef short bf16x8 __attribute__((ext_vector_type(8)));

__device__ __forceinline__ float fast_tanh(float x) {
    float e = __expf(2.0f * x);
    return 1.0f - __fdividef(2.0f, e + 1.0f);
}

// f32 -> bf16 bits (round-nearest-even)
__device__ __forceinline__ unsigned short f2b(float x) {
    unsigned u = __float_as_uint(x);
    unsigned r = (u + 0x7FFFu + ((u >> 16) & 1u)) >> 16;
    return (unsigned short)r;
}
__device__ __forceinline__ float b2f(unsigned short h) {
    return __uint_as_float(((unsigned)h) << 16);
}

// split 8 floats into hi/lo bf16 planes, packed as uint4 each
__device__ __forceinline__ void split_pack8(const float f[8], uint4& vh, uint4& vl) {
    unsigned short h[8], l[8];
#pragma unroll
    for (int j = 0; j < 8; ++j) {
        h[j] = f2b(f[j]);
        l[j] = f2b(f[j] - b2f(h[j]));
    }
    vh = make_uint4((unsigned)h[0] | ((unsigned)h[1] << 16), (unsigned)h[2] | ((unsigned)h[3] << 16),
                    (unsigned)h[4] | ((unsigned)h[5] << 16), (unsigned)h[6] | ((unsigned)h[7] << 16));
    vl = make_uint4((unsigned)l[0] | ((unsigned)l[1] << 16), (unsigned)l[2] | ((unsigned)l[3] << 16),
                    (unsigned)l[4] | ((unsigned)l[5] << 16), (unsigned)l[6] | ((unsigned)l[7] << 16));
}

// ---------------------------------------------------------------------------
// K1: RBF projection via split-bf16 MFMA.
// Block: 256 thr (4 waves), tile 64g x 128d, K-step 32.
// Wave tile 32g x 64d = 2x4 frags of 16x16x32 MFMA.
// acc += Al*Bh + Ah*Bl + Ah*Bh  (rel err ~2^-16, ~fp32).
// ---------------------------------------------------------------------------
__global__ __launch_bounds__(256, 2) void k_proj(const float* __restrict__ emb,
                                                 const float* __restrict__ pos,
                                                 const float* __restrict__ grd,
                                                 const float* __restrict__ sigma_p,
                                                 float* __restrict__ field) {
    __shared__ unsigned short sKh[64][40], sKl[64][40];
    __shared__ unsigned short sEh[128][40], sEl[128][40];

    const int t    = threadIdx.x;
    const int lane = t & 63;
    const int w    = t >> 6;
    const int wg   = w & 1;        // g half (32 rows)
    const int wd   = w >> 1;       // d half (64 cols)
    const int q    = lane >> 4;
    const int r16  = lane & 15;

    const int bt = blockIdx.z;
    const int g0 = blockIdx.y * 64;
    const int d0 = blockIdx.x * 128;

    const float sg = sigma_p[0];
    const float inv2s2 = 1.0f / (2.0f * sg * sg);

    const float* Eb = emb + (size_t)bt * N_ * D_;
    const float* Pb = pos + (size_t)bt * N_;

    const int kg = t >> 2;          // kern row 0..63
    const int k8 = (t & 3) * 8;     // kern k-slice
    const float xg = grd[(size_t)bt * G_ + g0 + kg];

    const int ek = t >> 5;          // E k 0..7
    const int ed = (t & 31) * 4;    // E col quad

    f32x4 acc[2][4];
#pragma unroll
    for (int m = 0; m < 2; ++m)
#pragma unroll
        for (int n = 0; n < 4; ++n) acc[m][n] = (f32x4){0.f, 0.f, 0.f, 0.f};

    for (int n0 = 0; n0 < N_; n0 += 32) {
        float4 ev[4];
#pragma unroll
        for (int s = 0; s < 4; ++s)
            ev[s] = *(const float4*)&Eb[(size_t)(n0 + ek + 8 * s) * D_ + d0 + ed];

        float kv[8];
#pragma unroll
        for (int j = 0; j < 8; ++j) {
            float p  = Pb[n0 + k8 + j];
            float dx = p - xg;
            kv[j] = __expf(-dx * dx * inv2s2);
        }

        __syncthreads();

        {
            uint4 vh, vl;
            split_pack8(kv, vh, vl);
            *(uint4*)&sKh[kg][k8] = vh;
            *(uint4*)&sKl[kg][k8] = vl;
        }
#pragma unroll
        for (int s = 0; s < 4; ++s) {
            int kk = ek + 8 * s;
            float f[4] = {ev[s].x, ev[s].y, ev[s].z, ev[s].w};
#pragma unroll
            for (int i = 0; i < 4; ++i) {
                unsigned short h = f2b(f[i]);
                sEh[ed + i][kk] = h;
                sEl[ed + i][kk] = f2b(f[i] - b2f(h));
            }
        }

        __syncthreads();

        bf16x8 ah[2], al_[2];
#pragma unroll
        for (int m = 0; m < 2; ++m) {
            int row = wg * 32 + m * 16 + r16;
            ah[m]  = *(const bf16x8*)&sKh[row][q * 8];
            al_[m] = *(const bf16x8*)&sKl[row][q * 8];
        }
#pragma unroll
        for (int n = 0; n < 4; ++n) {
            int row = wd * 64 + n * 16 + r16;
            bf16x8 bh = *(const bf16x8*)&sEh[row][q * 8];
            bf16x8 bl = *(const bf16x8*)&sEl[row][q * 8];
#pragma unroll
            for (int m = 0; m < 2; ++m) {
                f32x4 c = acc[m][n];
                c = __builtin_amdgcn_mfma_f32_16x16x32_bf16(al_[m], bh, c, 0, 0, 0);
                c = __builtin_amdgcn_mfma_f32_16x16x32_bf16(ah[m], bl, c, 0, 0, 0);
                c = __builtin_amdgcn_mfma_f32_16x16x32_bf16(ah[m], bh, c, 0, 0, 0);
                acc[m][n] = c;
            }
        }
    }

    // C/D layout: col=lane&15, row=(lane>>4)*4+reg (HW-verified mapping)
#pragma unroll
    for (int m = 0; m < 2; ++m) {
        int gr = g0 + wg * 32 + m * 16 + q * 4;
#pragma unroll
        for (int n = 0; n < 4; ++n) {
            int dc = d0 + wd * 64 + n * 16 + r16;
            f32x4 c = acc[m][n];
#pragma unroll
            for (int r = 0; r < 4; ++r)
                field[((size_t)bt * G_ + gr + r) * D_ + dc] = c[r];
        }
    }
}

// ---------------------------------------------------------------------------
// K2: diffusion step via split-bf16 MFMA.
// Tile 64 rows x 128 cols, grid (2,256)=512 blocks. K-step 32 over K=256.
// A = fin rows (already K-major); B = W_int staged transposed [e][k].
// Epilogue: laplacian + tanh update, per-lane scalar (64B-coalesced).
// ---------------------------------------------------------------------------
__global__ __launch_bounds__(256, 2) void k_diff(const float* __restrict__ fin,
                                                 float* __restrict__ fout,
                                                 const float* __restrict__ W,
                                                 const float* __restrict__ bint,
                                                 const float* __restrict__ alpha_p) {
    __shared__ unsigned short sAh[64][40], sAl[64][40];
    __shared__ unsigned short sWh[128][40], sWl[128][40];

    const int t    = threadIdx.x;
    const int lane = t & 63;
    const int w    = t >> 6;
    const int wg   = w & 1;        // 32-row half
    const int wd   = w >> 1;       // 64-col half
    const int q    = lane >> 4;
    const int r16  = lane & 15;

    const int r0 = blockIdx.y * 64;
    const int c0 = blockIdx.x * 128;

    const int ar = t >> 2;          // A row 0..63
    const int ak = (t & 3) * 8;     // A k-slice {0,8,16,24}
    const int ek = t >> 5;          // W k 0..7
    const int ed = (t & 31) * 4;    // W col quad

    f32x4 acc[2][4];
#pragma unroll
    for (int m = 0; m < 2; ++m)
#pragma unroll
        for (int n = 0; n < 4; ++n) acc[m][n] = (f32x4){0.f, 0.f, 0.f, 0.f};

    for (int k0 = 0; k0 < D_; k0 += 32) {
        float4 a0 = *(const float4*)&fin[(size_t)(r0 + ar) * D_ + k0 + ak];
        float4 a1 = *(const float4*)&fin[(size_t)(r0 + ar) * D_ + k0 + ak + 4];
        float4 wv[4];
#pragma unroll
        for (int s = 0; s < 4; ++s)
            wv[s] = *(const float4*)&W[(size_t)(k0 + ek + 8 * s) * D_ + c0 + ed];

        __syncthreads();

        {
            float fa[8] = {a0.x, a0.y, a0.z, a0.w, a1.x, a1.y, a1.z, a1.w};
            uint4 vh, vl;
            split_pack8(fa, vh, vl);
            *(uint4*)&sAh[ar][ak] = vh;
            *(uint4*)&sAl[ar][ak] = vl;
        }
#pragma unroll
        for (int s = 0; s < 4; ++s) {
            int kk = ek + 8 * s;
            float f[4] = {wv[s].x, wv[s].y, wv[s].z, wv[s].w};
#pragma unroll
            for (int i = 0; i < 4; ++i) {
                unsigned short h = f2b(f[i]);
                sWh[ed + i][kk] = h;
                sWl[ed + i][kk] = f2b(f[i] - b2f(h));
            }
        }

        __syncthreads();

        bf16x8 ah[2], al_[2];
#pragma unroll
        for (int m = 0; m < 2; ++m) {
            int row = wg * 32 + m * 16 + r16;
            ah[m]  = *(const bf16x8*)&sAh[row][q * 8];
            al_[m] = *(const bf16x8*)&sAl[row][q * 8];
        }
#pragma unroll
        for (int n = 0; n < 4; ++n) {
            int col = wd * 64 + n * 16 + r16;
            bf16x8 bh = *(const bf16x8*)&sWh[col][q * 8];
            bf16x8 bl = *(const bf16x8*)&sWl[col][q * 8];
#pragma unroll
            for (int m = 0; m < 2; ++m) {
                f32x4 c = acc[m][n];
                c = __builtin_amdgcn_mfma_f32_16x16x32_bf16(al_[m], bh, c, 0, 0, 0);
                c = __builtin_amdgcn_mfma_f32_16x16x32_bf16(ah[m], bl, c, 0, 0, 0);
                c = __builtin_amdgcn_mfma_f32_16x16x32_bf16(ah[m], bh, c, 0, 0, 0);
                acc[m][n] = c;
            }
        }
    }

    const float al = alpha_p[0];
#pragma unroll
    for (int m = 0; m < 2; ++m) {
#pragma unroll
        for (int n = 0; n < 4; ++n) {
            const int dc = c0 + wd * 64 + n * 16 + r16;
            const float bi = bint[dc];
            f32x4 c = acc[m][n];
#pragma unroll
            for (int r = 0; r < 4; ++r) {
                const int row = r0 + wg * 32 + m * 16 + q * 4 + r;
                const int g = row & (G_ - 1);
                const float fc = fin[(size_t)row * D_ + dc];
                const float fu = fin[(size_t)(g == 0 ? row : row - 1) * D_ + dc];
                const float fd = fin[(size_t)(g == G_ - 1 ? row : row + 1) * D_ + dc];
                const float y  = fast_tanh(c[r] + bi);
                fout[(size_t)row * D_ + dc] = fc + DT_ * (al * (fu + fd - 2.0f * fc) + y);
            }
        }
    }
}

// ---------------------------------------------------------------------------
// K3: sample + residual + LayerNorm1 (unchanged).
// ---------------------------------------------------------------------------
__global__ __launch_bounds__(256) void k_sample(const float* __restrict__ field,
                                                const float* __restrict__ emb,
                                                const float* __restrict__ pos,
                                                const float* __restrict__ g1,
                                                const float* __restrict__ b1,
                                                float* __restrict__ enh) {
    const int row  = blockIdx.x * 4 + (threadIdx.x >> 6);
    const int lane = threadIdx.x & 63;
    const int b    = row >> 12;
    const int d    = lane * 4;

    float p  = pos[row];
    float u  = p * (float)(G_ - 1);
    float fi = floorf(u);
    fi = fminf(fmaxf(fi, 0.0f), (float)(G_ - 2));
    int   i0 = (int)fi;
    float w  = u - fi;

    const float4 f0v = *(const float4*)&field[((size_t)(b << 10) + i0) * D_ + d];
    const float4 f1v = *(const float4*)&field[((size_t)(b << 10) + i0 + 1) * D_ + d];
    const float4 ev  = *(const float4*)&emb[(size_t)row * D_ + d];

    float y[4];
    y[0] = f0v.x + w * (f1v.x - f0v.x) + ev.x;
    y[1] = f0v.y + w * (f1v.y - f0v.y) + ev.y;
    y[2] = f0v.z + w * (f1v.z - f0v.z) + ev.z;
    y[3] = f0v.w + w * (f1v.w - f0v.w) + ev.w;

    float s1 = y[0] + y[1] + y[2] + y[3];
    float s2 = y[0]*y[0] + y[1]*y[1] + y[2]*y[2] + y[3]*y[3];
#pragma unroll
    for (int m = 1; m < 64; m <<= 1) {
        s1 += __shfl_xor(s1, m);
        s2 += __shfl_xor(s2, m);
    }
    float mu  = s1 * (1.0f / 256.0f);
    float var = s2 * (1.0f / 256.0f) - mu * mu;
    float rs  = rsqrtf(var + EPS_);

    const float4 gv = *(const float4*)&g1[d];
    const float4 bv = *(const float4*)&b1[d];
    float4 o;
    o.x = (y[0] - mu) * rs * gv.x + bv.x;
    o.y = (y[1] - mu) * rs * gv.y + bv.y;
    o.z = (y[2] - mu) * rs * gv.z + bv.z;
    o.w = (y[3] - mu) * rs * gv.w + bv.w;
    *(float4*)&enh[(size_t)row * D_ + d] = o;
}

// ---------------------------------------------------------------------------
// K4: out-proj + residual + LN2 via split-bf16 MFMA, in-place on d_out.
// Tile 32 rows x 256 cols (full width for fused LN2), grid 2048 blocks.
// A-operand = block's OWN 32 rows only -> in-place safe (disjoint ownership).
// acc -> LDS (aliased over staging, barrier-fenced) -> row-major LN epilogue.
// ---------------------------------------------------------------------------
__global__ __launch_bounds__(256, 2) void k_out(const float* __restrict__ enh,
                                                const float* __restrict__ W,
                                                const float* __restrict__ bo,
                                                const float* __restrict__ g2,
                                                const float* __restrict__ b2,
                                                float* __restrict__ out) {
    __shared__ __align__(16) char smem[46080];
    unsigned short (*sAh)[40] = (unsigned short(*)[40])(smem);            // 32x40
    unsigned short (*sAl)[40] = (unsigned short(*)[40])(smem + 2560);     // 32x40
    unsigned short (*sWh)[40] = (unsigned short(*)[40])(smem + 5120);     // 256x40
    unsigned short (*sWl)[40] = (unsigned short(*)[40])(smem + 25600);    // 256x40
    float (*sO)[260] = (float(*)[260])(smem);                             // 32x260 (reuse)

    const int t    = threadIdx.x;
    const int lane = t & 63;
    const int w    = t >> 6;
    const int wg   = w & 1;        // 16-row half
    const int wd   = w >> 1;       // 128-col half
    const int q    = lane >> 4;
    const int r16  = lane & 15;

    const int r0 = blockIdx.x * 32;

    const int arow = t >> 3;        // 0..31
    const int akq  = (t & 7) * 4;   // 0..28
    const int wk   = t >> 6;        // 0..3
    const int wed  = (t & 63) * 4;  // 0..252

    f32x4 acc[8];
#pragma unroll
    for (int n = 0; n < 8; ++n) acc[n] = (f32x4){0.f, 0.f, 0.f, 0.f};

    for (int k0 = 0; k0 < D_; k0 += 32) {
        float4 av = *(const float4*)&enh[(size_t)(r0 + arow) * D_ + k0 + akq];
        float4 wv[8];
#pragma unroll
        for (int s = 0; s < 8; ++s)
            wv[s] = *(const float4*)&W[(size_t)(k0 + wk + 4 * s) * D_ + wed];

        __syncthreads();

        {
            float fa[4] = {av.x, av.y, av.z, av.w};
            unsigned short h[4], l[4];
#pragma unroll
            for (int j = 0; j < 4; ++j) {
                h[j] = f2b(fa[j]);
                l[j] = f2b(fa[j] - b2f(h[j]));
            }
            *(uint2*)&sAh[arow][akq] = make_uint2((unsigned)h[0] | ((unsigned)h[1] << 16),
                                                  (unsigned)h[2] | ((unsigned)h[3] << 16));
            *(uint2*)&sAl[arow][akq] = make_uint2((unsigned)l[0] | ((unsigned)l[1] << 16),
                                                  (unsigned)l[2] | ((unsigned)l[3] << 16));
        }
#pragma unroll
        for (int s = 0; s < 8; ++s) {
            int kk = wk + 4 * s;
            float f[4] = {wv[s].x, wv[s].y, wv[s].z, wv[s].w};
#pragma unroll
            for (int i = 0; i < 4; ++i) {
                unsigned short h = f2b(f[i]);
                sWh[wed + i][kk] = h;
                sWl[wed + i][kk] = f2b(f[i] - b2f(h));
            }
        }

        __syncthreads();

        bf16x8 ah  = *(const bf16x8*)&sAh[wg * 16 + r16][q * 8];
        bf16x8 al_ = *(const bf16x8*)&sAl[wg * 16 + r16][q * 8];
#pragma unroll
        for (int n = 0; n < 8; ++n) {
            int col = wd * 128 + n * 16 + r16;
            bf16x8 bh = *(const bf16x8*)&sWh[col][q * 8];
            bf16x8 bl = *(const bf16x8*)&sWl[col][q * 8];
            f32x4 c = acc[n];
            c = __builtin_amdgcn_mfma_f32_16x16x32_bf16(al_, bh, c, 0, 0, 0);
            c = __builtin_amdgcn_mfma_f32_16x16x32_bf16(ah, bl, c, 0, 0, 0);
            c = __builtin_amdgcn_mfma_f32_16x16x32_bf16(ah, bh, c, 0, 0, 0);
            acc[n] = c;
        }
    }

    __syncthreads();   // all MFMA LDS reads done before aliasing sO over staging
#pragma unroll
    for (int n = 0; n < 8; ++n)
#pragma unroll
        for (int r = 0; r < 4; ++r)
            sO[wg * 16 + q * 4 + r][wd * 128 + n * 16 + r16] = acc[n][r];
    __syncthreads();

    // LN2 epilogue: 8 threads per row, 32 cols each
    const int er = t >> 3;
    const int ec = (t & 7) * 32;
    const size_t grow = (size_t)(r0 + er) * D_;

    float y[32];
    float s1 = 0.f, s2 = 0.f;
#pragma unroll
    for (int j = 0; j < 8; ++j) {
        float4 a  = *(const float4*)&sO[er][ec + j * 4];
        float4 bv = *(const float4*)&bo[ec + j * 4];
        float4 e  = *(const float4*)&enh[grow + ec + j * 4];
        float v0 = a.x + bv.x + e.x, v1 = a.y + bv.y + e.y;
        float v2 = a.z + bv.z + e.z, v3 = a.w + bv.w + e.w;
        y[j * 4 + 0] = v0; y[j * 4 + 1] = v1; y[j * 4 + 2] = v2; y[j * 4 + 3] = v3;
        s1 += v0 + v1 + v2 + v3;
        s2 += v0 * v0 + v1 * v1 + v2 * v2 + v3 * v3;
    }
#pragma unroll
    for (int m = 1; m < 8; m <<= 1) {
        s1 += __shfl_xor(s1, m);
        s2 += __shfl_xor(s2, m);
    }
    float mu  = s1 * (1.0f / 256.0f);
    float var = s2 * (1.0f / 256.0f) - mu * mu;
    float rs  = rsqrtf(var + EPS_);
#pragma unroll
    for (int j = 0; j < 8; ++j) {
        float4 gv  = *(const float4*)&g2[ec + j * 4];
        float4 b2v = *(const float4*)&b2[ec + j * 4];
        float4 o;
        o.x = (y[j * 4 + 0] - mu) * rs * gv.x + b2v.x;
        o.y = (y[j * 4 + 1] - mu) * rs * gv.y + b2v.y;
        o.z = (y[j * 4 + 2] - mu) * rs * gv.z + b2v.z;
        o.w = (y[j * 4 + 3] - mu) * rs * gv.w + b2v.w;
        *(float4*)&out[grow + ec + j * 4] = o;
    }
}

// ---------------------------------------------------------------------------
extern "C" void kernel_launch(void* const* d_in, const int* in_sizes, int n_in,
                              void* d_out, int out_size, void* d_ws, size_t ws_size,
                              hipStream_t stream) {
    const float* emb   = (const float*)d_in[0];
    const float* pos   = (const float*)d_in[1];
    const float* grd   = (const float*)d_in[2];
    const float* sigma = (const float*)d_in[3];
    const float* alpha = (const float*)d_in[4];
    const float* W_int = (const float*)d_in[5];
    const float* b_int = (const float*)d_in[6];
    const float* W_out = (const float*)d_in[7];
    const float* b_out = (const float*)d_in[8];
    const float* g1    = (const float*)d_in[9];
    const float* b1    = (const float*)d_in[10];
    const float* g2    = (const float*)d_in[11];
    const float* b2    = (const float*)d_in[12];
    float* out = (float*)d_out;

    float* f0 = (float*)d_ws;
    float* f1 = f0 + (size_t)B_ * G_ * D_;

    // 1) projection (split-bf16 MFMA), 512 blocks
    k_proj<<<dim3(D_ / 128, G_ / 64, B_), 256, 0, stream>>>(emb, pos, grd, sigma, f0);
    // 2) 4 diffusion steps (split-bf16 MFMA), 512 blocks each, ping-pong ends in f0
    k_diff<<<dim3(D_ / 128, (B_ * G_) / 64), 256, 0, stream>>>(f0, f1, W_int, b_int, alpha);
    k_diff<<<dim3(D_ / 128, (B_ * G_) / 64), 256, 0, stream>>>(f1, f0, W_int, b_int, alpha);
    k_diff<<<dim3(D_ / 128, (B_ * G_) / 64), 256, 0, stream>>>(f0, f1, W_int, b_int, alpha);
    k_diff<<<dim3(D_ / 128, (B_ * G_) / 64), 256, 0, stream>>>(f1, f0, W_int, b_int, alpha);
    // 3) sample + residual + LN1 -> d_out
    k_sample<<<(B_ * N_) / 4, 256, 0, stream>>>(f0, emb, pos, g1, b1, out);
    // 4) out-proj + residual + LN2 (split-bf16 MFMA), in-place, 2048 blocks
    k_out<<<(B_ * N_) / 32, 256, 0, stream>>>(out, W_out, b_out, g2, b2, out);
}

// Round 7
// 704.135 us; speedup vs baseline: 1.6209x; 1.6209x over previous
//
#include <hip/hip_runtime.h>
#include <math.h>

#define B_ 16
#define N_ 4096
#define G_ 1024
#define D_ 256
#define DT_ 0.01f
#define EPS_ 1e-5f

typedef float f32x4 __attribute__((ext_vector_type(4)));
typedef short bf16x8 __attribute__((ext_vector_type(8)));
typedef unsigned short u16;

__device__ __forceinline__ float fast_tanh(float x) {
    float e = __expf(2.0f * x);
    return 1.0f - __fdividef(2.0f, e + 1.0f);
}

// f32 -> bf16 bits (round-nearest-even)
__device__ __forceinline__ u16 f2b(float x) {
    unsigned u = __float_as_uint(x);
    unsigned r = (u + 0x7FFFu + ((u >> 16) & 1u)) >> 16;
    return (u16)r;
}
__device__ __forceinline__ float b2f(u16 h) {
    return __uint_as_float(((unsigned)h) << 16);
}

// split 8 floats into hi/lo bf16 planes, packed as uint4 each
__device__ __forceinline__ void split_pack8(const float f[8], uint4& vh, uint4& vl) {
    u16 h[8], l[8];
#pragma unroll
    for (int j = 0; j < 8; ++j) {
        h[j] = f2b(f[j]);
        l[j] = f2b(f[j] - b2f(h[j]));
    }
    vh = make_uint4((unsigned)h[0] | ((unsigned)h[1] << 16), (unsigned)h[2] | ((unsigned)h[3] << 16),
                    (unsigned)h[4] | ((unsigned)h[5] << 16), (unsigned)h[6] | ((unsigned)h[7] << 16));
    vl = make_uint4((unsigned)l[0] | ((unsigned)l[1] << 16), (unsigned)l[2] | ((unsigned)l[3] << 16),
                    (unsigned)l[4] | ((unsigned)l[5] << 16), (unsigned)l[6] | ((unsigned)l[7] << 16));
}

// same split, producing register bf16x8 fragments
__device__ __forceinline__ void split8(const float f[8], bf16x8& h8, bf16x8& l8) {
    union { uint4 u; bf16x8 v; } H, L;
    split_pack8(f, H.u, L.u);
    h8 = H.v; l8 = L.v;
}

// ===========================================================================
// TIER A (ws_size >= 101.2 MB): prepass-transposed operands, no LDS scatter
// ===========================================================================

// --- prepass: W_int and W_out -> transposed bf16 h/l planes [c][k] ----------
__global__ __launch_bounds__(256) void k_wsplit(const float* __restrict__ Wi,
                                                const float* __restrict__ Wo,
                                                u16* __restrict__ wbase) {
    const float* W = blockIdx.y ? Wo : Wi;
    u16* Th = wbase + (size_t)blockIdx.y * 131072;   // [c][k] h-plane
    u16* Tl = Th + 65536;                            // [c][k] l-plane
    int e0 = (blockIdx.x * 256 + threadIdx.x) * 2;
#pragma unroll
    for (int i = 0; i < 2; ++i) {
        int e = e0 + i;                // e = c*256 + k
        int c = e >> 8, k = e & 255;
        float v = W[(size_t)k * D_ + c];
        u16 h = f2b(v);
        Th[e] = h;
        Tl[e] = f2b(v - b2f(h));
    }
}

// --- prepass: E [b][n][d] f32 -> Eh/El [b][d][n] bf16 (transpose + split) ---
__global__ __launch_bounds__(256) void k_esplit(const float* __restrict__ emb,
                                                u16* __restrict__ Eh,
                                                u16* __restrict__ El) {
    __shared__ float sT[64][68];
    const int t  = threadIdx.x;
    const int b  = blockIdx.z;
    const int n0 = blockIdx.y * 64;
    const int d0 = blockIdx.x * 64;
    const float* Eb = emb + (size_t)b * N_ * D_;

#pragma unroll
    for (int s = 0; s < 4; ++s) {
        int fi  = t + 256 * s;
        int row = fi >> 4;
        int c4  = (fi & 15) * 4;
        float4 v = *(const float4*)&Eb[(size_t)(n0 + row) * D_ + d0 + c4];
        *(float4*)&sT[row][c4] = v;
    }
    __syncthreads();

    const int d  = t >> 2;
    const int ng = t & 3;
    u16 h[16], l[16];
#pragma unroll
    for (int i = 0; i < 16; ++i) {
        float v = sT[ng * 16 + i][d];
        h[i] = f2b(v);
        l[i] = f2b(v - b2f(h[i]));
    }
    size_t ob = ((size_t)b * D_ + d0 + d) * N_ + n0 + ng * 16;
    uint4 H0 = make_uint4((unsigned)h[0] | ((unsigned)h[1] << 16), (unsigned)h[2] | ((unsigned)h[3] << 16),
                          (unsigned)h[4] | ((unsigned)h[5] << 16), (unsigned)h[6] | ((unsigned)h[7] << 16));
    uint4 H1 = make_uint4((unsigned)h[8] | ((unsigned)h[9] << 16), (unsigned)h[10] | ((unsigned)h[11] << 16),
                          (unsigned)h[12] | ((unsigned)h[13] << 16), (unsigned)h[14] | ((unsigned)h[15] << 16));
    uint4 L0 = make_uint4((unsigned)l[0] | ((unsigned)l[1] << 16), (unsigned)l[2] | ((unsigned)l[3] << 16),
                          (unsigned)l[4] | ((unsigned)l[5] << 16), (unsigned)l[6] | ((unsigned)l[7] << 16));
    uint4 L1 = make_uint4((unsigned)l[8] | ((unsigned)l[9] << 16), (unsigned)l[10] | ((unsigned)l[11] << 16),
                          (unsigned)l[12] | ((unsigned)l[13] << 16), (unsigned)l[14] | ((unsigned)l[15] << 16));
    *(uint4*)&Eh[ob]     = H0;
    *(uint4*)&Eh[ob + 8] = H1;
    *(uint4*)&El[ob]     = L0;
    *(uint4*)&El[ob + 8] = L1;
}

// --- K1: RBF projection; kern in LDS (vectorized), E-frags direct from L2 ---
__global__ __launch_bounds__(256, 2) void k_proj_a(const u16* __restrict__ Eh,
                                                   const u16* __restrict__ El,
                                                   const float* __restrict__ pos,
                                                   const float* __restrict__ grd,
                                                   const float* __restrict__ sigma_p,
                                                   float* __restrict__ field) {
    __shared__ u16 sKh[64][40], sKl[64][40];

    const int t    = threadIdx.x;
    const int lane = t & 63;
    const int w    = t >> 6;
    const int wg   = w & 1;        // g half (32 rows)
    const int wd   = w >> 1;       // d half (64 cols)
    const int q    = lane >> 4;
    const int r16  = lane & 15;

    const int bt = blockIdx.z;
    const int g0 = blockIdx.y * 64;
    const int d0 = blockIdx.x * 128;

    const float sg = sigma_p[0];
    const float inv2s2 = 1.0f / (2.0f * sg * sg);
    const float* Pb = pos + (size_t)bt * N_;

    const int kg = t >> 2;
    const int k8 = (t & 3) * 8;
    const float xg = grd[(size_t)bt * G_ + g0 + kg];

    const u16* Ehb = Eh + (size_t)bt * D_ * N_;
    const u16* Elb = El + (size_t)bt * D_ * N_;
    size_t cb[4];
#pragma unroll
    for (int n = 0; n < 4; ++n)
        cb[n] = (size_t)(d0 + wd * 64 + n * 16 + r16) * N_ + q * 8;

    f32x4 acc[2][4];
#pragma unroll
    for (int m = 0; m < 2; ++m)
#pragma unroll
        for (int n = 0; n < 4; ++n) acc[m][n] = (f32x4){0.f, 0.f, 0.f, 0.f};

    for (int n0 = 0; n0 < N_; n0 += 32) {
        // B-fragments: one dwordx4 per (n, plane) straight from L2-resident Eh/El
        bf16x8 bh[4], bl[4];
#pragma unroll
        for (int n = 0; n < 4; ++n) {
            bh[n] = *(const bf16x8*)&Ehb[cb[n] + n0];
            bl[n] = *(const bf16x8*)&Elb[cb[n] + n0];
        }
        // kern values (8 per thread), positions vectorized
        float4 p0 = *(const float4*)&Pb[n0 + k8];
        float4 p1 = *(const float4*)&Pb[n0 + k8 + 4];
        float pv[8] = {p0.x, p0.y, p0.z, p0.w, p1.x, p1.y, p1.z, p1.w};
        float kv[8];
#pragma unroll
        for (int j = 0; j < 8; ++j) {
            float dx = pv[j] - xg;
            kv[j] = __expf(-dx * dx * inv2s2);
        }

        __syncthreads();
        {
            uint4 vh, vl;
            split_pack8(kv, vh, vl);
            *(uint4*)&sKh[kg][k8] = vh;
            *(uint4*)&sKl[kg][k8] = vl;
        }
        __syncthreads();

        bf16x8 ah[2], al_[2];
#pragma unroll
        for (int m = 0; m < 2; ++m) {
            int row = wg * 32 + m * 16 + r16;
            ah[m]  = *(const bf16x8*)&sKh[row][q * 8];
            al_[m] = *(const bf16x8*)&sKl[row][q * 8];
        }
#pragma unroll
        for (int n = 0; n < 4; ++n)
#pragma unroll
            for (int m = 0; m < 2; ++m) {
                f32x4 c = acc[m][n];
                c = __builtin_amdgcn_mfma_f32_16x16x32_bf16(al_[m], bh[n], c, 0, 0, 0);
                c = __builtin_amdgcn_mfma_f32_16x16x32_bf16(ah[m], bl[n], c, 0, 0, 0);
                c = __builtin_amdgcn_mfma_f32_16x16x32_bf16(ah[m], bh[n], c, 0, 0, 0);
                acc[m][n] = c;
            }
    }

    // C/D layout: col=lane&15, row=(lane>>4)*4+reg (HW-verified)
#pragma unroll
    for (int m = 0; m < 2; ++m) {
        int gr = g0 + wg * 32 + m * 16 + q * 4;
#pragma unroll
        for (int n = 0; n < 4; ++n) {
            int dc = d0 + wd * 64 + n * 16 + r16;
            f32x4 c = acc[m][n];
#pragma unroll
            for (int r = 0; r < 4; ++r)
                field[((size_t)bt * G_ + gr + r) * D_ + dc] = c[r];
        }
    }
}

// --- K2: diffusion step; zero LDS, zero barriers ---------------------------
__global__ __launch_bounds__(256, 2) void k_diff_a(const float* __restrict__ fin,
                                                   float* __restrict__ fout,
                                                   const u16* __restrict__ Wh,
                                                   const u16* __restrict__ Wl,
                                                   const float* __restrict__ bint,
                                                   const float* __restrict__ alpha_p) {
    const int t    = threadIdx.x;
    const int lane = t & 63;
    const int w    = t >> 6;
    const int wg   = w & 1;
    const int wd   = w >> 1;
    const int q    = lane >> 4;
    const int r16  = lane & 15;

    const int r0 = blockIdx.y * 64;
    const int c0 = blockIdx.x * 128;

    size_t arow[2], cb[4];
#pragma unroll
    for (int m = 0; m < 2; ++m)
        arow[m] = (size_t)(r0 + wg * 32 + m * 16 + r16) * D_ + q * 8;
#pragma unroll
    for (int n = 0; n < 4; ++n)
        cb[n] = (size_t)(c0 + wd * 64 + n * 16 + r16) * D_ + q * 8;

    f32x4 acc[2][4];
#pragma unroll
    for (int m = 0; m < 2; ++m)
#pragma unroll
        for (int n = 0; n < 4; ++n) acc[m][n] = (f32x4){0.f, 0.f, 0.f, 0.f};

    for (int k0 = 0; k0 < D_; k0 += 32) {
        bf16x8 ah[2], al_[2];
#pragma unroll
        for (int m = 0; m < 2; ++m) {
            float4 a0 = *(const float4*)&fin[arow[m] + k0];
            float4 a1 = *(const float4*)&fin[arow[m] + k0 + 4];
            float fa[8] = {a0.x, a0.y, a0.z, a0.w, a1.x, a1.y, a1.z, a1.w};
            split8(fa, ah[m], al_[m]);
        }
#pragma unroll
        for (int n = 0; n < 4; ++n) {
            bf16x8 bh = *(const bf16x8*)&Wh[cb[n] + k0];
            bf16x8 bl = *(const bf16x8*)&Wl[cb[n] + k0];
#pragma unroll
            for (int m = 0; m < 2; ++m) {
                f32x4 c = acc[m][n];
                c = __builtin_amdgcn_mfma_f32_16x16x32_bf16(al_[m], bh, c, 0, 0, 0);
                c = __builtin_amdgcn_mfma_f32_16x16x32_bf16(ah[m], bl, c, 0, 0, 0);
                c = __builtin_amdgcn_mfma_f32_16x16x32_bf16(ah[m], bh, c, 0, 0, 0);
                acc[m][n] = c;
            }
        }
    }

    const float al = alpha_p[0];
#pragma unroll
    for (int m = 0; m < 2; ++m) {
#pragma unroll
        for (int n = 0; n < 4; ++n) {
            const int dc = c0 + wd * 64 + n * 16 + r16;
            const float bi = bint[dc];
            f32x4 c = acc[m][n];
#pragma unroll
            for (int r = 0; r < 4; ++r) {
                const int row = r0 + wg * 32 + m * 16 + q * 4 + r;
                const int g = row & (G_ - 1);
                const float fc = fin[(size_t)row * D_ + dc];
                const float fu = fin[(size_t)(g == 0 ? row : row - 1) * D_ + dc];
                const float fd = fin[(size_t)(g == G_ - 1 ? row : row + 1) * D_ + dc];
                const float y  = fast_tanh(c[r] + bi);
                fout[(size_t)row * D_ + dc] = fc + DT_ * (al * (fu + fd - 2.0f * fc) + y);
            }
        }
    }
}

// --- K4: out-proj + residual + LN2; LDS only for the C transpose (sO) ------
__global__ __launch_bounds__(256, 2) void k_out_a(const float* __restrict__ enh,
                                                  const u16* __restrict__ Wh,
                                                  const u16* __restrict__ Wl,
                                                  const float* __restrict__ bo,
                                                  const float* __restrict__ g2,
                                                  const float* __restrict__ b2,
                                                  float* __restrict__ out) {
    __shared__ float sO[32][260];

    const int t    = threadIdx.x;
    const int lane = t & 63;
    const int w    = t >> 6;
    const int wg   = w & 1;        // 16-row half
    const int wd   = w >> 1;       // 128-col half
    const int q    = lane >> 4;
    const int r16  = lane & 15;

    const int r0 = blockIdx.x * 32;

    size_t arow = (size_t)(r0 + wg * 16 + r16) * D_ + q * 8;
    size_t cb[8];
#pragma unroll
    for (int n = 0; n < 8; ++n)
        cb[n] = (size_t)(wd * 128 + n * 16 + r16) * D_ + q * 8;

    f32x4 acc[8];
#pragma unroll
    for (int n = 0; n < 8; ++n) acc[n] = (f32x4){0.f, 0.f, 0.f, 0.f};

    for (int k0 = 0; k0 < D_; k0 += 32) {
        float4 a0 = *(const float4*)&enh[arow + k0];
        float4 a1 = *(const float4*)&enh[arow + k0 + 4];
        float fa[8] = {a0.x, a0.y, a0.z, a0.w, a1.x, a1.y, a1.z, a1.w};
        bf16x8 ah, al_;
        split8(fa, ah, al_);
#pragma unroll
        for (int n = 0; n < 8; ++n) {
            bf16x8 bh = *(const bf16x8*)&Wh[cb[n] + k0];
            bf16x8 bl = *(const bf16x8*)&Wl[cb[n] + k0];
            f32x4 c = acc[n];
            c = __builtin_amdgcn_mfma_f32_16x16x32_bf16(al_, bh, c, 0, 0, 0);
            c = __builtin_amdgcn_mfma_f32_16x16x32_bf16(ah, bl, c, 0, 0, 0);
            c = __builtin_amdgcn_mfma_f32_16x16x32_bf16(ah, bh, c, 0, 0, 0);
            acc[n] = c;
        }
    }

#pragma unroll
    for (int n = 0; n < 8; ++n)
#pragma unroll
        for (int r = 0; r < 4; ++r)
            sO[wg * 16 + q * 4 + r][wd * 128 + n * 16 + r16] = acc[n][r];
    __syncthreads();

    const int er = t >> 3;
    const int ec = (t & 7) * 32;
    const size_t grow = (size_t)(r0 + er) * D_;

    float y[32];
    float s1 = 0.f, s2 = 0.f;
#pragma unroll
    for (int j = 0; j < 8; ++j) {
        float4 a  = *(const float4*)&sO[er][ec + j * 4];
        float4 bv = *(const float4*)&bo[ec + j * 4];
        float4 e  = *(const float4*)&enh[grow + ec + j * 4];
        float v0 = a.x + bv.x + e.x, v1 = a.y + bv.y + e.y;
        float v2 = a.z + bv.z + e.z, v3 = a.w + bv.w + e.w;
        y[j * 4 + 0] = v0; y[j * 4 + 1] = v1; y[j * 4 + 2] = v2; y[j * 4 + 3] = v3;
        s1 += v0 + v1 + v2 + v3;
        s2 += v0 * v0 + v1 * v1 + v2 * v2 + v3 * v3;
    }
#pragma unroll
    for (int m = 1; m < 8; m <<= 1) {
        s1 += __shfl_xor(s1, m);
        s2 += __shfl_xor(s2, m);
    }
    float mu  = s1 * (1.0f / 256.0f);
    float var = s2 * (1.0f / 256.0f) - mu * mu;
    float rs  = rsqrtf(var + EPS_);
#pragma unroll
    for (int j = 0; j < 8; ++j) {
        float4 gv  = *(const float4*)&g2[ec + j * 4];
        float4 b2v = *(const float4*)&b2[ec + j * 4];
        float4 o;
        o.x = (y[j * 4 + 0] - mu) * rs * gv.x + b2v.x;
        o.y = (y[j * 4 + 1] - mu) * rs * gv.y + b2v.y;
        o.z = (y[j * 4 + 2] - mu) * rs * gv.z + b2v.z;
        o.w = (y[j * 4 + 3] - mu) * rs * gv.w + b2v.w;
        *(float4*)&out[grow + ec + j * 4] = o;
    }
}

// --- K3: sample + residual + LN1 (shared by both tiers) --------------------
__global__ __launch_bounds__(256) void k_sample(const float* __restrict__ field,
                                                const float* __restrict__ emb,
                                                const float* __restrict__ pos,
                                                const float* __restrict__ g1,
                                                const float* __restrict__ b1,
                                                float* __restrict__ enh) {
    const int row  = blockIdx.x * 4 + (threadIdx.x >> 6);
    const int lane = threadIdx.x & 63;
    const int b    = row >> 12;
    const int d    = lane * 4;

    float p  = pos[row];
    float u  = p * (float)(G_ - 1);
    float fi = floorf(u);
    fi = fminf(fmaxf(fi, 0.0f), (float)(G_ - 2));
    int   i0 = (int)fi;
    float ww = u - fi;

    const float4 f0v = *(const float4*)&field[((size_t)(b << 10) + i0) * D_ + d];
    const float4 f1v = *(const float4*)&field[((size_t)(b << 10) + i0 + 1) * D_ + d];
    const float4 ev  = *(const float4*)&emb[(size_t)row * D_ + d];

    float y[4];
    y[0] = f0v.x + ww * (f1v.x - f0v.x) + ev.x;
    y[1] = f0v.y + ww * (f1v.y - f0v.y) + ev.y;
    y[2] = f0v.z + ww * (f1v.z - f0v.z) + ev.z;
    y[3] = f0v.w + ww * (f1v.w - f0v.w) + ev.w;

    float s1 = y[0] + y[1] + y[2] + y[3];
    float s2 = y[0]*y[0] + y[1]*y[1] + y[2]*y[2] + y[3]*y[3];
#pragma unroll
    for (int m = 1; m < 64; m <<= 1) {
        s1 += __shfl_xor(s1, m);
        s2 += __shfl_xor(s2, m);
    }
    float mu  = s1 * (1.0f / 256.0f);
    float var = s2 * (1.0f / 256.0f) - mu * mu;
    float rs  = rsqrtf(var + EPS_);

    const float4 gv = *(const float4*)&g1[d];
    const float4 bv = *(const float4*)&b1[d];
    float4 o;
    o.x = (y[0] - mu) * rs * gv.x + bv.x;
    o.y = (y[1] - mu) * rs * gv.y + bv.y;
    o.z = (y[2] - mu) * rs * gv.z + bv.z;
    o.w = (y[3] - mu) * rs * gv.w + bv.w;
    *(float4*)&enh[(size_t)row * D_ + d] = o;
}

// ===========================================================================
// TIER B fallback (ws too small): round-6 kernels verbatim (known-passing)
// ===========================================================================
__global__ __launch_bounds__(256, 2) void k_proj_b(const float* __restrict__ emb,
                                                   const float* __restrict__ pos,
                                                   const float* __restrict__ grd,
                                                   const float* __restrict__ sigma_p,
                                                   float* __restrict__ field) {
    __shared__ u16 sKh[64][40], sKl[64][40];
    __shared__ u16 sEh[128][40], sEl[128][40];

    const int t = threadIdx.x, lane = t & 63, w = t >> 6;
    const int wg = w & 1, wd = w >> 1, q = lane >> 4, r16 = lane & 15;
    const int bt = blockIdx.z, g0 = blockIdx.y * 64, d0 = blockIdx.x * 128;
    const float sg = sigma_p[0], inv2s2 = 1.0f / (2.0f * sg * sg);
    const float* Eb = emb + (size_t)bt * N_ * D_;
    const float* Pb = pos + (size_t)bt * N_;
    const int kg = t >> 2, k8 = (t & 3) * 8;
    const float xg = grd[(size_t)bt * G_ + g0 + kg];
    const int ek = t >> 5, ed = (t & 31) * 4;

    f32x4 acc[2][4];
#pragma unroll
    for (int m = 0; m < 2; ++m)
#pragma unroll
        for (int n = 0; n < 4; ++n) acc[m][n] = (f32x4){0.f, 0.f, 0.f, 0.f};

    for (int n0 = 0; n0 < N_; n0 += 32) {
        float4 ev[4];
#pragma unroll
        for (int s = 0; s < 4; ++s)
            ev[s] = *(const float4*)&Eb[(size_t)(n0 + ek + 8 * s) * D_ + d0 + ed];
        float kv[8];
#pragma unroll
        for (int j = 0; j < 8; ++j) {
            float p = Pb[n0 + k8 + j];
            float dx = p - xg;
            kv[j] = __expf(-dx * dx * inv2s2);
        }
        __syncthreads();
        {
            uint4 vh, vl;
            split_pack8(kv, vh, vl);
            *(uint4*)&sKh[kg][k8] = vh;
            *(uint4*)&sKl[kg][k8] = vl;
        }
#pragma unroll
        for (int s = 0; s < 4; ++s) {
            int kk = ek + 8 * s;
            float f[4] = {ev[s].x, ev[s].y, ev[s].z, ev[s].w};
#pragma unroll
            for (int i = 0; i < 4; ++i) {
                u16 h = f2b(f[i]);
                sEh[ed + i][kk] = h;
                sEl[ed + i][kk] = f2b(f[i] - b2f(h));
            }
        }
        __syncthreads();
        bf16x8 ah[2], al_[2];
#pragma unroll
        for (int m = 0; m < 2; ++m) {
            int row = wg * 32 + m * 16 + r16;
            ah[m]  = *(const bf16x8*)&sKh[row][q * 8];
            al_[m] = *(const bf16x8*)&sKl[row][q * 8];
        }
#pragma unroll
        for (int n = 0; n < 4; ++n) {
            int row = wd * 64 + n * 16 + r16;
            bf16x8 bh = *(const bf16x8*)&sEh[row][q * 8];
            bf16x8 bl = *(const bf16x8*)&sEl[row][q * 8];
#pragma unroll
            for (int m = 0; m < 2; ++m) {
                f32x4 c = acc[m][n];
                c = __builtin_amdgcn_mfma_f32_16x16x32_bf16(al_[m], bh, c, 0, 0, 0);
                c = __builtin_amdgcn_mfma_f32_16x16x32_bf16(ah[m], bl, c, 0, 0, 0);
                c = __builtin_amdgcn_mfma_f32_16x16x32_bf16(ah[m], bh, c, 0, 0, 0);
                acc[m][n] = c;
            }
        }
    }
#pragma unroll
    for (int m = 0; m < 2; ++m) {
        int gr = g0 + wg * 32 + m * 16 + q * 4;
#pragma unroll
        for (int n = 0; n < 4; ++n) {
            int dc = d0 + wd * 64 + n * 16 + r16;
            f32x4 c = acc[m][n];
#pragma unroll
            for (int r = 0; r < 4; ++r)
                field[((size_t)bt * G_ + gr + r) * D_ + dc] = c[r];
        }
    }
}

__global__ __launch_bounds__(256, 2) void k_diff_b(const float* __restrict__ fin,
                                                   float* __restrict__ fout,
                                                   const float* __restrict__ W,
                                                   const float* __restrict__ bint,
                                                   const float* __restrict__ alpha_p) {
    __shared__ u16 sAh[64][40], sAl[64][40];
    __shared__ u16 sWh[128][40], sWl[128][40];

    const int t = threadIdx.x, lane = t & 63, w = t >> 6;
    const int wg = w & 1, wd = w >> 1, q = lane >> 4, r16 = lane & 15;
    const int r0 = blockIdx.y * 64, c0 = blockIdx.x * 128;
    const int ar = t >> 2, ak = (t & 3) * 8, ek = t >> 5, ed = (t & 31) * 4;

    f32x4 acc[2][4];
#pragma unroll
    for (int m = 0; m < 2; ++m)
#pragma unroll
        for (int n = 0; n < 4; ++n) acc[m][n] = (f32x4){0.f, 0.f, 0.f, 0.f};

    for (int k0 = 0; k0 < D_; k0 += 32) {
        float4 a0 = *(const float4*)&fin[(size_t)(r0 + ar) * D_ + k0 + ak];
        float4 a1 = *(const float4*)&fin[(size_t)(r0 + ar) * D_ + k0 + ak + 4];
        float4 wv[4];
#pragma unroll
        for (int s = 0; s < 4; ++s)
            wv[s] = *(const float4*)&W[(size_t)(k0 + ek + 8 * s) * D_ + c0 + ed];
        __syncthreads();
        {
            float fa[8] = {a0.x, a0.y, a0.z, a0.w, a1.x, a1.y, a1.z, a1.w};
            uint4 vh, vl;
            split_pack8(fa, vh, vl);
            *(uint4*)&sAh[ar][ak] = vh;
            *(uint4*)&sAl[ar][ak] = vl;
        }
#pragma unroll
        for (int s = 0; s < 4; ++s) {
            int kk = ek + 8 * s;
            float f[4] = {wv[s].x, wv[s].y, wv[s].z, wv[s].w};
#pragma unroll
            for (int i = 0; i < 4; ++i) {
                u16 h = f2b(f[i]);
                sWh[ed + i][kk] = h;
                sWl[ed + i][kk] = f2b(f[i] - b2f(h));
            }
        }
        __syncthreads();
        bf16x8 ah[2], al_[2];
#pragma unroll
        for (int m = 0; m < 2; ++m) {
            int row = wg * 32 + m * 16 + r16;
            ah[m]  = *(const bf16x8*)&sAh[row][q * 8];
            al_[m] = *(const bf16x8*)&sAl[row][q * 8];
        }
#pragma unroll
        for (int n = 0; n < 4; ++n) {
            int col = wd * 64 + n * 16 + r16;
            bf16x8 bh = *(const bf16x8*)&sWh[col][q * 8];
            bf16x8 bl = *(const bf16x8*)&sWl[col][q * 8];
#pragma unroll
            for (int m = 0; m < 2; ++m) {
                f32x4 c = acc[m][n];
                c = __builtin_amdgcn_mfma_f32_16x16x32_bf16(al_[m], bh, c, 0, 0, 0);
                c = __builtin_amdgcn_mfma_f32_16x16x32_bf16(ah[m], bl, c, 0, 0, 0);
                c = __builtin_amdgcn_mfma_f32_16x16x32_bf16(ah[m], bh, c, 0, 0, 0);
                acc[m][n] = c;
            }
        }
    }

    const float al = alpha_p[0];
#pragma unroll
    for (int m = 0; m < 2; ++m) {
#pragma unroll
        for (int n = 0; n < 4; ++n) {
            const int dc = c0 + wd * 64 + n * 16 + r16;
            const float bi = bint[dc];
            f32x4 c = acc[m][n];
#pragma unroll
            for (int r = 0; r < 4; ++r) {
                const int row = r0 + wg * 32 + m * 16 + q * 4 + r;
                const int g = row & (G_ - 1);
                const float fc = fin[(size_t)row * D_ + dc];
                const float fu = fin[(size_t)(g == 0 ? row : row - 1) * D_ + dc];
                const float fd = fin[(size_t)(g == G_ - 1 ? row : row + 1) * D_ + dc];
                const float y  = fast_tanh(c[r] + bi);
                fout[(size_t)row * D_ + dc] = fc + DT_ * (al * (fu + fd - 2.0f * fc) + y);
            }
        }
    }
}

__global__ __launch_bounds__(256, 2) void k_out_b(const float* __restrict__ enh,
                                                  const float* __restrict__ W,
                                                  const float* __restrict__ bo,
                                                  const float* __restrict__ g2,
                                                  const float* __restrict__ b2,
                                                  float* __restrict__ out) {
    __shared__ __align__(16) char smem[46080];
    u16 (*sAh)[40] = (u16(*)[40])(smem);
    u16 (*sAl)[40] = (u16(*)[40])(smem + 2560);
    u16 (*sWh)[40] = (u16(*)[40])(smem + 5120);
    u16 (*sWl)[40] = (u16(*)[40])(smem + 25600);
    float (*sO)[260] = (float(*)[260])(smem);

    const int t = threadIdx.x, lane = t & 63, w = t >> 6;
    const int wg = w & 1, wd = w >> 1, q = lane >> 4, r16 = lane & 15;
    const int r0 = blockIdx.x * 32;
    const int arow = t >> 3, akq = (t & 7) * 4, wk = t >> 6, wed = (t & 63) * 4;

    f32x4 acc[8];
#pragma unroll
    for (int n = 0; n < 8; ++n) acc[n] = (f32x4){0.f, 0.f, 0.f, 0.f};

    for (int k0 = 0; k0 < D_; k0 += 32) {
        float4 av = *(const float4*)&enh[(size_t)(r0 + arow) * D_ + k0 + akq];
        float4 wv[8];
#pragma unroll
        for (int s = 0; s < 8; ++s)
            wv[s] = *(const float4*)&W[(size_t)(k0 + wk + 4 * s) * D_ + wed];
        __syncthreads();
        {
            float fa[4] = {av.x, av.y, av.z, av.w};
            u16 h[4], l[4];
#pragma unroll
            for (int j = 0; j < 4; ++j) {
                h[j] = f2b(fa[j]);
                l[j] = f2b(fa[j] - b2f(h[j]));
            }
            *(uint2*)&sAh[arow][akq] = make_uint2((unsigned)h[0] | ((unsigned)h[1] << 16),
                                                  (unsigned)h[2] | ((unsigned)h[3] << 16));
            *(uint2*)&sAl[arow][akq] = make_uint2((unsigned)l[0] | ((unsigned)l[1] << 16),
                                                  (unsigned)l[2] | ((unsigned)l[3] << 16));
        }
#pragma unroll
        for (int s = 0; s < 8; ++s) {
            int kk = wk + 4 * s;
            float f[4] = {wv[s].x, wv[s].y, wv[s].z, wv[s].w};
#pragma unroll
            for (int i = 0; i < 4; ++i) {
                u16 h = f2b(f[i]);
                sWh[wed + i][kk] = h;
                sWl[wed + i][kk] = f2b(f[i] - b2f(h));
            }
        }
        __syncthreads();
        bf16x8 ah  = *(const bf16x8*)&sAh[wg * 16 + r16][q * 8];
        bf16x8 al_ = *(const bf16x8*)&sAl[wg * 16 + r16][q * 8];
#pragma unroll
        for (int n = 0; n < 8; ++n) {
            int col = wd * 128 + n * 16 + r16;
            bf16x8 bh = *(const bf16x8*)&sWh[col][q * 8];
            bf16x8 bl = *(const bf16x8*)&sWl[col][q * 8];
            f32x4 c = acc[n];
            c = __builtin_amdgcn_mfma_f32_16x16x32_bf16(al_, bh, c, 0, 0, 0);
            c = __builtin_amdgcn_mfma_f32_16x16x32_bf16(ah, bl, c, 0, 0, 0);
            c = __builtin_amdgcn_mfma_f32_16x16x32_bf16(ah, bh, c, 0, 0, 0);
            acc[n] = c;
        }
    }

    __syncthreads();
#pragma unroll
    for (int n = 0; n < 8; ++n)
#pragma unroll
        for (int r = 0; r < 4; ++r)
            sO[wg * 16 + q * 4 + r][wd * 128 + n * 16 + r16] = acc[n][r];
    __syncthreads();

    const int er = t >> 3;
    const int ec = (t & 7) * 32;
    const size_t grow = (size_t)(r0 + er) * D_;

    float y[32];
    float s1 = 0.f, s2 = 0.f;
#pragma unroll
    for (int j = 0; j < 8; ++j) {
        float4 a  = *(const float4*)&sO[er][ec + j * 4];
        float4 bv = *(const float4*)&bo[ec + j * 4];
        float4 e  = *(const float4*)&enh[grow + ec + j * 4];
        float v0 = a.x + bv.x + e.x, v1 = a.y + bv.y + e.y;
        float v2 = a.z + bv.z + e.z, v3 = a.w + bv.w + e.w;
        y[j * 4 + 0] = v0; y[j * 4 + 1] = v1; y[j * 4 + 2] = v2; y[j * 4 + 3] = v3;
        s1 += v0 + v1 + v2 + v3;
        s2 += v0 * v0 + v1 * v1 + v2 * v2 + v3 * v3;
    }
#pragma unroll
    for (int m = 1; m < 8; m <<= 1) {
        s1 += __shfl_xor(s1, m);
        s2 += __shfl_xor(s2, m);
    }
    float mu  = s1 * (1.0f / 256.0f);
    float var = s2 * (1.0f / 256.0f) - mu * mu;
    float rs  = rsqrtf(var + EPS_);
#pragma unroll
    for (int j = 0; j < 8; ++j) {
        float4 gv  = *(const float4*)&g2[ec + j * 4];
        float4 b2v = *(const float4*)&b2[ec + j * 4];
        float4 o;
        o.x = (y[j * 4 + 0] - mu) * rs * gv.x + b2v.x;
        o.y = (y[j * 4 + 1] - mu) * rs * gv.y + b2v.y;
        o.z = (y[j * 4 + 2] - mu) * rs * gv.z + b2v.z;
        o.w = (y[j * 4 + 3] - mu) * rs * gv.w + b2v.w;
        *(float4*)&out[grow + ec + j * 4] = o;
    }
}

// ===========================================================================
extern "C" void kernel_launch(void* const* d_in, const int* in_sizes, int n_in,
                              void* d_out, int out_size, void* d_ws, size_t ws_size,
                              hipStream_t stream) {
    const float* emb   = (const float*)d_in[0];
    const float* pos   = (const float*)d_in[1];
    const float* grd   = (const float*)d_in[2];
    const float* sigma = (const float*)d_in[3];
    const float* alpha = (const float*)d_in[4];
    const float* W_int = (const float*)d_in[5];
    const float* b_int = (const float*)d_in[6];
    const float* W_out = (const float*)d_in[7];
    const float* b_out = (const float*)d_in[8];
    const float* g1    = (const float*)d_in[9];
    const float* b1    = (const float*)d_in[10];
    const float* g2    = (const float*)d_in[11];
    const float* b2    = (const float*)d_in[12];
    float* out = (float*)d_out;

    // Tier-A workspace layout
    const size_t W_BYTES  = 524288;                    // 4x bf16 [256][256]
    const size_t F_BYTES  = (size_t)B_ * G_ * D_ * 4;  // 16.78 MB
    const size_t E_BYTES  = (size_t)B_ * D_ * N_ * 2;  // 33.55 MB per plane
    const size_t NEED = W_BYTES + 2 * F_BYTES + 2 * E_BYTES;  // 101,187,584

    if (ws_size >= NEED) {
        char* ws = (char*)d_ws;
        u16*   Wih = (u16*)ws;                       // [c][k] W_int hi
        u16*   Wil = Wih + 65536;
        u16*   Woh = Wih + 131072;                   // [c][k] W_out hi
        u16*   Wol = Wih + 196608;
        float* f0  = (float*)(ws + W_BYTES);
        float* f1  = (float*)(ws + W_BYTES + F_BYTES);
        u16*   Eh  = (u16*)(ws + W_BYTES + 2 * F_BYTES);
        u16*   El  = (u16*)(ws + W_BYTES + 2 * F_BYTES + E_BYTES);

        k_wsplit<<<dim3(128, 2), 256, 0, stream>>>(W_int, W_out, Wih);
        k_esplit<<<dim3(4, 64, 16), 256, 0, stream>>>(emb, Eh, El);
        k_proj_a<<<dim3(2, 16, 16), 256, 0, stream>>>(Eh, El, pos, grd, sigma, f0);
        k_diff_a<<<dim3(2, 256), 256, 0, stream>>>(f0, f1, Wih, Wil, b_int, alpha);
        k_diff_a<<<dim3(2, 256), 256, 0, stream>>>(f1, f0, Wih, Wil, b_int, alpha);
        k_diff_a<<<dim3(2, 256), 256, 0, stream>>>(f0, f1, Wih, Wil, b_int, alpha);
        k_diff_a<<<dim3(2, 256), 256, 0, stream>>>(f1, f0, Wih, Wil, b_int, alpha);
        k_sample<<<(B_ * N_) / 4, 256, 0, stream>>>(f0, emb, pos, g1, b1, out);
        k_out_a<<<(B_ * N_) / 32, 256, 0, stream>>>(out, Woh, Wol, b_out, g2, b2, out);
    } else {
        // Fallback: round-6 path (needs only 33.6 MB)
        float* f0 = (float*)d_ws;
        float* f1 = f0 + (size_t)B_ * G_ * D_;
        k_proj_b<<<dim3(2, 16, 16), 256, 0, stream>>>(emb, pos, grd, sigma, f0);
        k_diff_b<<<dim3(2, 256), 256, 0, stream>>>(f0, f1, W_int, b_int, alpha);
        k_diff_b<<<dim3(2, 256), 256, 0, stream>>>(f1, f0, W_int, b_int, alpha);
        k_diff_b<<<dim3(2, 256), 256, 0, stream>>>(f0, f1, W_int, b_int, alpha);
        k_diff_b<<<dim3(2, 256), 256, 0, stream>>>(f1, f0, W_int, b_int, alpha);
        k_sample<<<(B_ * N_) / 4, 256, 0, stream>>>(f0, emb, pos, g1, b1, out);
        k_out_b<<<(B_ * N_) / 32, 256, 0, stream>>>(out, W_out, b_out, g2, b2, out);
    }
}

// Round 11
// 648.438 us; speedup vs baseline: 1.7601x; 1.0859x over previous
//
#include <hip/hip_runtime.h>
#include <hip/hip_bf16.h>
#include <math.h>

#define B_ 16
#define N_ 4096
#define G_ 1024
#define D_ 256
#define DT_ 0.01f
#define EPS_ 1e-5f

typedef float f32x4 __attribute__((ext_vector_type(4)));
typedef short bf16x8 __attribute__((ext_vector_type(8)));
typedef unsigned short u16;

__device__ __forceinline__ float fast_tanh(float x) {
    float e = __expf(2.0f * x);
    return 1.0f - __fdividef(2.0f, e + 1.0f);
}

// f32 -> bf16 bits (round-nearest-even)
__device__ __forceinline__ u16 f2b(float x) {
    unsigned u = __float_as_uint(x);
    unsigned r = (u + 0x7FFFu + ((u >> 16) & 1u)) >> 16;
    return (u16)r;
}
__device__ __forceinline__ float b2f(u16 h) {
    return __uint_as_float(((unsigned)h) << 16);
}

// split 8 floats into hi/lo bf16 planes, packed as uint4 each
__device__ __forceinline__ void split_pack8(const float f[8], uint4& vh, uint4& vl) {
    u16 h[8], l[8];
#pragma unroll
    for (int j = 0; j < 8; ++j) {
        h[j] = f2b(f[j]);
        l[j] = f2b(f[j] - b2f(h[j]));
    }
    vh = make_uint4((unsigned)h[0] | ((unsigned)h[1] << 16), (unsigned)h[2] | ((unsigned)h[3] << 16),
                    (unsigned)h[4] | ((unsigned)h[5] << 16), (unsigned)h[6] | ((unsigned)h[7] << 16));
    vl = make_uint4((unsigned)l[0] | ((unsigned)l[1] << 16), (unsigned)l[2] | ((unsigned)l[3] << 16),
                    (unsigned)l[4] | ((unsigned)l[5] << 16), (unsigned)l[6] | ((unsigned)l[7] << 16));
}

// same split, producing register bf16x8 fragments
__device__ __forceinline__ void split8(const float f[8], bf16x8& h8, bf16x8& l8) {
    union { uint4 u; bf16x8 v; } H, L;
    split_pack8(f, H.u, L.u);
    h8 = H.v; l8 = L.v;
}

// ===========================================================================
// TIER A (ws_size >= 101.2 MB)
// ===========================================================================

// --- prepass: W_int and W_out -> transposed bf16 h/l planes [c][k] ----------
__global__ __launch_bounds__(256) void k_wsplit(const float* __restrict__ Wi,
                                                const float* __restrict__ Wo,
                                                u16* __restrict__ wbase) {
    const float* W = blockIdx.y ? Wo : Wi;
    u16* Th = wbase + (size_t)blockIdx.y * 131072;
    u16* Tl = Th + 65536;
    int e0 = (blockIdx.x * 256 + threadIdx.x) * 2;
#pragma unroll
    for (int i = 0; i < 2; ++i) {
        int e = e0 + i;                // e = c*256 + k
        int c = e >> 8, k = e & 255;
        float v = W[(size_t)k * D_ + c];
        u16 h = f2b(v);
        Th[e] = h;
        Tl[e] = f2b(v - b2f(h));
    }
}

// --- prepass: E [b][n][d] f32 -> Eh/El [b][d][n] bf16 (transpose + split) ---
__global__ __launch_bounds__(256) void k_esplit(const float* __restrict__ emb,
                                                u16* __restrict__ Eh,
                                                u16* __restrict__ El) {
    __shared__ float sT[64][68];
    const int t  = threadIdx.x;
    const int b  = blockIdx.z;
    const int n0 = blockIdx.y * 64;
    const int d0 = blockIdx.x * 64;
    const float* Eb = emb + (size_t)b * N_ * D_;

#pragma unroll
    for (int s = 0; s < 4; ++s) {
        int fi  = t + 256 * s;
        int row = fi >> 4;
        int c4  = (fi & 15) * 4;
        float4 v = *(const float4*)&Eb[(size_t)(n0 + row) * D_ + d0 + c4];
        *(float4*)&sT[row][c4] = v;
    }
    __syncthreads();

    const int d  = t >> 2;
    const int ng = t & 3;
    u16 h[16], l[16];
#pragma unroll
    for (int i = 0; i < 16; ++i) {
        float v = sT[ng * 16 + i][d];
        h[i] = f2b(v);
        l[i] = f2b(v - b2f(h[i]));
    }
    size_t ob = ((size_t)b * D_ + d0 + d) * N_ + n0 + ng * 16;
    uint4 H0 = make_uint4((unsigned)h[0] | ((unsigned)h[1] << 16), (unsigned)h[2] | ((unsigned)h[3] << 16),
                          (unsigned)h[4] | ((unsigned)h[5] << 16), (unsigned)h[6] | ((unsigned)h[7] << 16));
    uint4 H1 = make_uint4((unsigned)h[8] | ((unsigned)h[9] << 16), (unsigned)h[10] | ((unsigned)h[11] << 16),
                          (unsigned)h[12] | ((unsigned)h[13] << 16), (unsigned)h[14] | ((unsigned)h[15] << 16));
    uint4 L0 = make_uint4((unsigned)l[0] | ((unsigned)l[1] << 16), (unsigned)l[2] | ((unsigned)l[3] << 16),
                          (unsigned)l[4] | ((unsigned)l[5] << 16), (unsigned)l[6] | ((unsigned)l[7] << 16));
    uint4 L1 = make_uint4((unsigned)l[8] | ((unsigned)l[9] << 16), (unsigned)l[10] | ((unsigned)l[11] << 16),
                          (unsigned)l[12] | ((unsigned)l[13] << 16), (unsigned)l[14] | ((unsigned)l[15] << 16));
    *(uint4*)&Eh[ob]     = H0;
    *(uint4*)&Eh[ob + 8] = H1;
    *(uint4*)&El[ob]     = L0;
    *(uint4*)&El[ob + 8] = L1;
}

// --- K1: RBF projection, kern-in-register, no LDS, no barriers, split-K x4 -
__global__ __launch_bounds__(256, 2) void k_proj_c(const u16* __restrict__ Eh,
                                                   const u16* __restrict__ El,
                                                   const float* __restrict__ pos,
                                                   const float* __restrict__ grd,
                                                   const float* __restrict__ sigma_p,
                                                   float* __restrict__ P0,
                                                   float* __restrict__ P1,
                                                   float* __restrict__ P2,
                                                   float* __restrict__ P3) {
    const int t    = threadIdx.x;
    const int lane = t & 63;
    const int w    = t >> 6;
    const int q    = lane >> 4;     // k-group 0..3
    const int r16  = lane & 15;

    const int d0 = blockIdx.x * 64;
    const int g0 = blockIdx.y * 256 + w * 64;
    const int bt = blockIdx.z >> 2;
    const int ks = blockIdx.z & 3;

    float* dst = (ks == 0) ? P0 : (ks == 1) ? P1 : (ks == 2) ? P2 : P3;

    const float sg   = sigma_p[0];
    const float negc = -1.0f / (2.0f * sg * sg);
    const float* Pb  = pos + (size_t)bt * N_;

    float xs[4];
#pragma unroll
    for (int m = 0; m < 4; ++m)
        xs[m] = grd[(size_t)bt * G_ + g0 + m * 16 + r16];

    const u16* Ehb = Eh + (size_t)bt * D_ * N_;
    const u16* Elb = El + (size_t)bt * D_ * N_;
    unsigned cb[4];
#pragma unroll
    for (int n = 0; n < 4; ++n)
        cb[n] = (unsigned)((d0 + n * 16 + r16) * N_ + ks * 1024 + q * 8);

    f32x4 acc[4][4];
#pragma unroll
    for (int m = 0; m < 4; ++m)
#pragma unroll
        for (int n = 0; n < 4; ++n) acc[m][n] = (f32x4){0.f, 0.f, 0.f, 0.f};

    const int kbase = ks * 1024;
    for (int kk = 0; kk < 1024; kk += 32) {
        bf16x8 bh[4], bl[4];
#pragma unroll
        for (int n = 0; n < 4; ++n) {
            bh[n] = *(const bf16x8*)&Ehb[cb[n] + kk];
            bl[n] = *(const bf16x8*)&Elb[cb[n] + kk];
        }
        float4 p0 = *(const float4*)&Pb[kbase + kk + q * 8];
        float4 p1 = *(const float4*)&Pb[kbase + kk + q * 8 + 4];
        float pv[8] = {p0.x, p0.y, p0.z, p0.w, p1.x, p1.y, p1.z, p1.w};

        bf16x8 ah[4], al_[4];
#pragma unroll
        for (int m = 0; m < 4; ++m) {
            float ev[8];
#pragma unroll
            for (int j = 0; j < 8; ++j) {
                float dx = pv[j] - xs[m];
                ev[j] = __expf(dx * dx * negc);
            }
            split8(ev, ah[m], al_[m]);
        }

#pragma unroll
        for (int n = 0; n < 4; ++n)
#pragma unroll
            for (int m = 0; m < 4; ++m) {
                f32x4 c = acc[m][n];
                c = __builtin_amdgcn_mfma_f32_16x16x32_bf16(al_[m], bh[n], c, 0, 0, 0);
                c = __builtin_amdgcn_mfma_f32_16x16x32_bf16(ah[m], bl[n], c, 0, 0, 0);
                c = __builtin_amdgcn_mfma_f32_16x16x32_bf16(ah[m], bh[n], c, 0, 0, 0);
                acc[m][n] = c;
            }
    }

    // C/D layout: col=lane&15, row=(lane>>4)*4+reg (HW-verified)
#pragma unroll
    for (int m = 0; m < 4; ++m) {
        int gr = g0 + m * 16 + q * 4;
#pragma unroll
        for (int n = 0; n < 4; ++n) {
            int dc = d0 + n * 16 + r16;
            f32x4 c = acc[m][n];
#pragma unroll
            for (int r = 0; r < 4; ++r)
                dst[((size_t)bt * G_ + gr + r) * D_ + dc] = c[r];
        }
    }
}

// --- sum the 4 split-K partials into P0 ------------------------------------
__global__ __launch_bounds__(256) void k_kadd(float* __restrict__ P0,
                                              const float* __restrict__ P1,
                                              const float* __restrict__ P2,
                                              const float* __restrict__ P3) {
    const int i = blockIdx.x * 256 + threadIdx.x;
    const int STRIDE = 262144;
#pragma unroll
    for (int k = 0; k < 4; ++k) {
        int idx = i + k * STRIDE;
        float4 a = *(const float4*)&P0[idx * 4];
        float4 b = *(const float4*)&P1[idx * 4];
        float4 c = *(const float4*)&P2[idx * 4];
        float4 d = *(const float4*)&P3[idx * 4];
        a.x += b.x + c.x + d.x;
        a.y += b.y + c.y + d.y;
        a.z += b.z + c.z + d.z;
        a.w += b.w + c.w + d.w;
        *(float4*)&P0[idx * 4] = a;
    }
}

// --- K2: diffusion step; zero LDS, zero barriers ---------------------------
__global__ __launch_bounds__(256, 2) void k_diff_a(const float* __restrict__ fin,
                                                   float* __restrict__ fout,
                                                   const u16* __restrict__ Wh,
                                                   const u16* __restrict__ Wl,
                                                   const float* __restrict__ bint,
                                                   const float* __restrict__ alpha_p) {
    const int t    = threadIdx.x;
    const int lane = t & 63;
    const int w    = t >> 6;
    const int wg   = w & 1;
    const int wd   = w >> 1;
    const int q    = lane >> 4;
    const int r16  = lane & 15;

    const int r0 = blockIdx.y * 64;
    const int c0 = blockIdx.x * 128;

    size_t arow[2], cb[4];
#pragma unroll
    for (int m = 0; m < 2; ++m)
        arow[m] = (size_t)(r0 + wg * 32 + m * 16 + r16) * D_ + q * 8;
#pragma unroll
    for (int n = 0; n < 4; ++n)
        cb[n] = (size_t)(c0 + wd * 64 + n * 16 + r16) * D_ + q * 8;

    f32x4 acc[2][4];
#pragma unroll
    for (int m = 0; m < 2; ++m)
#pragma unroll
        for (int n = 0; n < 4; ++n) acc[m][n] = (f32x4){0.f, 0.f, 0.f, 0.f};

    for (int k0 = 0; k0 < D_; k0 += 32) {
        bf16x8 ah[2], al_[2];
#pragma unroll
        for (int m = 0; m < 2; ++m) {
            float4 a0 = *(const float4*)&fin[arow[m] + k0];
            float4 a1 = *(const float4*)&fin[arow[m] + k0 + 4];
            float fa[8] = {a0.x, a0.y, a0.z, a0.w, a1.x, a1.y, a1.z, a1.w};
            split8(fa, ah[m], al_[m]);
        }
#pragma unroll
        for (int n = 0; n < 4; ++n) {
            bf16x8 bh = *(const bf16x8*)&Wh[cb[n] + k0];
            bf16x8 bl = *(const bf16x8*)&Wl[cb[n] + k0];
#pragma unroll
            for (int m = 0; m < 2; ++m) {
                f32x4 c = acc[m][n];
                c = __builtin_amdgcn_mfma_f32_16x16x32_bf16(al_[m], bh, c, 0, 0, 0);
                c = __builtin_amdgcn_mfma_f32_16x16x32_bf16(ah[m], bl, c, 0, 0, 0);
                c = __builtin_amdgcn_mfma_f32_16x16x32_bf16(ah[m], bh, c, 0, 0, 0);
                acc[m][n] = c;
            }
        }
    }

    const float al = alpha_p[0];
#pragma unroll
    for (int m = 0; m < 2; ++m) {
#pragma unroll
        for (int n = 0; n < 4; ++n) {
            const int dc = c0 + wd * 64 + n * 16 + r16;
            const float bi = bint[dc];
            f32x4 c = acc[m][n];
#pragma unroll
            for (int r = 0; r < 4; ++r) {
                const int row = r0 + wg * 32 + m * 16 + q * 4 + r;
                const int g = row & (G_ - 1);
                const float fc = fin[(size_t)row * D_ + dc];
                const float fu = fin[(size_t)(g == 0 ? row : row - 1) * D_ + dc];
                const float fd = fin[(size_t)(g == G_ - 1 ? row : row + 1) * D_ + dc];
                const float y  = fast_tanh(c[r] + bi);
                fout[(size_t)row * D_ + dc] = fc + DT_ * (al * (fu + fd - 2.0f * fc) + y);
            }
        }
    }
}

// --- K4: out-proj + residual + LN2 -----------------------------------------
__global__ __launch_bounds__(256, 2) void k_out_a(const float* __restrict__ enh,
                                                  const u16* __restrict__ Wh,
                                                  const u16* __restrict__ Wl,
                                                  const float* __restrict__ bo,
                                                  const float* __restrict__ g2,
                                                  const float* __restrict__ b2,
                                                  float* __restrict__ out) {
    __shared__ float sO[32][260];

    const int t    = threadIdx.x;
    const int lane = t & 63;
    const int w    = t >> 6;
    const int wg   = w & 1;
    const int wd   = w >> 1;
    const int q    = lane >> 4;
    const int r16  = lane & 15;

    const int r0 = blockIdx.x * 32;

    size_t arow = (size_t)(r0 + wg * 16 + r16) * D_ + q * 8;
    size_t cb[8];
#pragma unroll
    for (int n = 0; n < 8; ++n)
        cb[n] = (size_t)(wd * 128 + n * 16 + r16) * D_ + q * 8;

    f32x4 acc[8];
#pragma unroll
    for (int n = 0; n < 8; ++n) acc[n] = (f32x4){0.f, 0.f, 0.f, 0.f};

    for (int k0 = 0; k0 < D_; k0 += 32) {
        float4 a0 = *(const float4*)&enh[arow + k0];
        float4 a1 = *(const float4*)&enh[arow + k0 + 4];
        float fa[8] = {a0.x, a0.y, a0.z, a0.w, a1.x, a1.y, a1.z, a1.w};
        bf16x8 ah, al_;
        split8(fa, ah, al_);
#pragma unroll
        for (int n = 0; n < 8; ++n) {
            bf16x8 bh = *(const bf16x8*)&Wh[cb[n] + k0];
            bf16x8 bl = *(const bf16x8*)&Wl[cb[n] + k0];
            f32x4 c = acc[n];
            c = __builtin_amdgcn_mfma_f32_16x16x32_bf16(al_, bh, c, 0, 0, 0);
            c = __builtin_amdgcn_mfma_f32_16x16x32_bf16(ah, bl, c, 0, 0, 0);
            c = __builtin_amdgcn_mfma_f32_16x16x32_bf16(ah, bh, c, 0, 0, 0);
            acc[n] = c;
        }
    }

#pragma unroll
    for (int n = 0; n < 8; ++n)
#pragma unroll
        for (int r = 0; r < 4; ++r)
            sO[wg * 16 + q * 4 + r][wd * 128 + n * 16 + r16] = acc[n][r];
    __syncthreads();

    const int er = t >> 3;
    const int ec = (t & 7) * 32;
    const size_t grow = (size_t)(r0 + er) * D_;

    float y[32];
    float s1 = 0.f, s2 = 0.f;
#pragma unroll
    for (int j = 0; j < 8; ++j) {
        float4 a  = *(const float4*)&sO[er][ec + j * 4];
        float4 bv = *(const float4*)&bo[ec + j * 4];
        float4 e  = *(const float4*)&enh[grow + ec + j * 4];
        float v0 = a.x + bv.x + e.x, v1 = a.y + bv.y + e.y;
        float v2 = a.z + bv.z + e.z, v3 = a.w + bv.w + e.w;
        y[j * 4 + 0] = v0; y[j * 4 + 1] = v1; y[j * 4 + 2] = v2; y[j * 4 + 3] = v3;
        s1 += v0 + v1 + v2 + v3;
        s2 += v0 * v0 + v1 * v1 + v2 * v2 + v3 * v3;
    }
#pragma unroll
    for (int m = 1; m < 8; m <<= 1) {
        s1 += __shfl_xor(s1, m);
        s2 += __shfl_xor(s2, m);
    }
    float mu  = s1 * (1.0f / 256.0f);
    float var = s2 * (1.0f / 256.0f) - mu * mu;
    float rs  = rsqrtf(var + EPS_);
#pragma unroll
    for (int j = 0; j < 8; ++j) {
        float4 gv  = *(const float4*)&g2[ec + j * 4];
        float4 b2v = *(const float4*)&b2[ec + j * 4];
        float4 o;
        o.x = (y[j * 4 + 0] - mu) * rs * gv.x + b2v.x;
        o.y = (y[j * 4 + 1] - mu) * rs * gv.y + b2v.y;
        o.z = (y[j * 4 + 2] - mu) * rs * gv.z + b2v.z;
        o.w = (y[j * 4 + 3] - mu) * rs * gv.w + b2v.w;
        *(float4*)&out[grow + ec + j * 4] = o;
    }
}

// --- K3: sample + residual + LN1 -------------------------------------------
__global__ __launch_bounds__(256) void k_sample(const float* __restrict__ field,
                                                const float* __restrict__ emb,
                                                const float* __restrict__ pos,
                                                const float* __restrict__ g1,
                                                const float* __restrict__ b1,
                                                float* __restrict__ enh) {
    const int row  = blockIdx.x * 4 + (threadIdx.x >> 6);
    const int lane = threadIdx.x & 63;
    const int b    = row >> 12;
    const int d    = lane * 4;

    float p  = pos[row];
    float u  = p * (float)(G_ - 1);
    float fi = floorf(u);
    fi = fminf(fmaxf(fi, 0.0f), (float)(G_ - 2));
    int   i0 = (int)fi;
    float ww = u - fi;

    const float4 f0v = *(const float4*)&field[((size_t)(b << 10) + i0) * D_ + d];
    const float4 f1v = *(const float4*)&field[((size_t)(b << 10) + i0 + 1) * D_ + d];
    const float4 ev  = *(const float4*)&emb[(size_t)row * D_ + d];

    float y[4];
    y[0] = f0v.x + ww * (f1v.x - f0v.x) + ev.x;
    y[1] = f0v.y + ww * (f1v.y - f0v.y) + ev.y;
    y[2] = f0v.z + ww * (f1v.z - f0v.z) + ev.z;
    y[3] = f0v.w + ww * (f1v.w - f0v.w) + ev.w;

    float s1 = y[0] + y[1] + y[2] + y[3];
    float s2 = y[0]*y[0] + y[1]*y[1] + y[2]*y[2] + y[3]*y[3];
#pragma unroll
    for (int m = 1; m < 64; m <<= 1) {
        s1 += __shfl_xor(s1, m);
        s2 += __shfl_xor(s2, m);
    }
    float mu  = s1 * (1.0f / 256.0f);
    float var = s2 * (1.0f / 256.0f) - mu * mu;
    float rs  = rsqrtf(var + EPS_);

    const float4 gv = *(const float4*)&g1[d];
    const float4 bv = *(const float4*)&b1[d];
    float4 o;
    o.x = (y[0] - mu) * rs * gv.x + bv.x;
    o.y = (y[1] - mu) * rs * gv.y + bv.y;
    o.z = (y[2] - mu) * rs * gv.z + bv.z;
    o.w = (y[3] - mu) * rs * gv.w + bv.w;
    *(float4*)&enh[(size_t)row * D_ + d] = o;
}

// ===========================================================================
// TIER B fallback (ws too small): round-6 kernels verbatim (known-passing)
// ===========================================================================
__global__ __launch_bounds__(256, 2) void k_proj_b(const float* __restrict__ emb,
                                                   const float* __restrict__ pos,
                                                   const float* __restrict__ grd,
                                                   const float* __restrict__ sigma_p,
                                                   float* __restrict__ field) {
    __shared__ u16 sKh[64][40], sKl[64][40];
    __shared__ u16 sEh[128][40], sEl[128][40];

    const int t = threadIdx.x, lane = t & 63, w = t >> 6;
    const int wg = w & 1, wd = w >> 1, q = lane >> 4, r16 = lane & 15;
    const int bt = blockIdx.z, g0 = blockIdx.y * 64, d0 = blockIdx.x * 128;
    const float sg = sigma_p[0], inv2s2 = 1.0f / (2.0f * sg * sg);
    const float* Eb = emb + (size_t)bt * N_ * D_;
    const float* Pb = pos + (size_t)bt * N_;
    const int kg = t >> 2, k8 = (t & 3) * 8;
    const float xg = grd[(size_t)bt * G_ + g0 + kg];
    const int ek = t >> 5, ed = (t & 31) * 4;

    f32x4 acc[2][4];
#pragma unroll
    for (int m = 0; m < 2; ++m)
#pragma unroll
        for (int n = 0; n < 4; ++n) acc[m][n] = (f32x4){0.f, 0.f, 0.f, 0.f};

    for (int n0 = 0; n0 < N_; n0 += 32) {
        float4 ev[4];
#pragma unroll
        for (int s = 0; s < 4; ++s)
            ev[s] = *(const float4*)&Eb[(size_t)(n0 + ek + 8 * s) * D_ + d0 + ed];
        float kv[8];
#pragma unroll
        for (int j = 0; j < 8; ++j) {
            float p = Pb[n0 + k8 + j];
            float dx = p - xg;
            kv[j] = __expf(-dx * dx * inv2s2);
        }
        __syncthreads();
        {
            uint4 vh, vl;
            split_pack8(kv, vh, vl);
            *(uint4*)&sKh[kg][k8] = vh;
            *(uint4*)&sKl[kg][k8] = vl;
        }
#pragma unroll
        for (int s = 0; s < 4; ++s) {
            int kk = ek + 8 * s;
            float f[4] = {ev[s].x, ev[s].y, ev[s].z, ev[s].w};
#pragma unroll
            for (int i = 0; i < 4; ++i) {
                u16 h = f2b(f[i]);
                sEh[ed + i][kk] = h;
                sEl[ed + i][kk] = f2b(f[i] - b2f(h));
            }
        }
        __syncthreads();
        bf16x8 ah[2], al_[2];
#pragma unroll
        for (int m = 0; m < 2; ++m) {
            int row = wg * 32 + m * 16 + r16;
            ah[m]  = *(const bf16x8*)&sKh[row][q * 8];
            al_[m] = *(const bf16x8*)&sKl[row][q * 8];
        }
#pragma unroll
        for (int n = 0; n < 4; ++n) {
            int row = wd * 64 + n * 16 + r16;
            bf16x8 bh = *(const bf16x8*)&sEh[row][q * 8];
            bf16x8 bl = *(const bf16x8*)&sEl[row][q * 8];
#pragma unroll
            for (int m = 0; m < 2; ++m) {
                f32x4 c = acc[m][n];
                c = __builtin_amdgcn_mfma_f32_16x16x32_bf16(al_[m], bh, c, 0, 0, 0);
                c = __builtin_amdgcn_mfma_f32_16x16x32_bf16(ah[m], bl, c, 0, 0, 0);
                c = __builtin_amdgcn_mfma_f32_16x16x32_bf16(ah[m], bh, c, 0, 0, 0);
                acc[m][n] = c;
            }
        }
    }
#pragma unroll
    for (int m = 0; m < 2; ++m) {
        int gr = g0 + wg * 32 + m * 16 + q * 4;
#pragma unroll
        for (int n = 0; n < 4; ++n) {
            int dc = d0 + wd * 64 + n * 16 + r16;
            f32x4 c = acc[m][n];
#pragma unroll
            for (int r = 0; r < 4; ++r)
                field[((size_t)bt * G_ + gr + r) * D_ + dc] = c[r];
        }
    }
}

__global__ __launch_bounds__(256, 2) void k_diff_b(const float* __restrict__ fin,
                                                   float* __restrict__ fout,
                                                   const float* __restrict__ W,
                                                   const float* __restrict__ bint,
                                                   const float* __restrict__ alpha_p) {
    __shared__ u16 sAh[64][40], sAl[64][40];
    __shared__ u16 sWh[128][40], sWl[128][40];

    const int t = threadIdx.x, lane = t & 63, w = t >> 6;
    const int wg = w & 1, wd = w >> 1, q = lane >> 4, r16 = lane & 15;
    const int r0 = blockIdx.y * 64, c0 = blockIdx.x * 128;
    const int ar = t >> 2, ak = (t & 3) * 8, ek = t >> 5, ed = (t & 31) * 4;

    f32x4 acc[2][4];
#pragma unroll
    for (int m = 0; m < 2; ++m)
#pragma unroll
        for (int n = 0; n < 4; ++n) acc[m][n] = (f32x4){0.f, 0.f, 0.f, 0.f};

    for (int k0 = 0; k0 < D_; k0 += 32) {
        float4 a0 = *(const float4*)&fin[(size_t)(r0 + ar) * D_ + k0 + ak];
        float4 a1 = *(const float4*)&fin[(size_t)(r0 + ar) * D_ + k0 + ak + 4];
        float4 wv[4];
#pragma unroll
        for (int s = 0; s < 4; ++s)
            wv[s] = *(const float4*)&W[(size_t)(k0 + ek + 8 * s) * D_ + c0 + ed];
        __syncthreads();
        {
            float fa[8] = {a0.x, a0.y, a0.z, a0.w, a1.x, a1.y, a1.z, a1.w};
            uint4 vh, vl;
            split_pack8(fa, vh, vl);
            *(uint4*)&sAh[ar][ak] = vh;
            *(uint4*)&sAl[ar][ak] = vl;
        }
#pragma unroll
        for (int s = 0; s < 4; ++s) {
            int kk = ek + 8 * s;
            float f[4] = {wv[s].x, wv[s].y, wv[s].z, wv[s].w};
#pragma unroll
            for (int i = 0; i < 4; ++i) {
                u16 h = f2b(f[i]);
                sWh[ed + i][kk] = h;
                sWl[ed + i][kk] = f2b(f[i] - b2f(h));
            }
        }
        __syncthreads();
        bf16x8 ah[2], al_[2];
#pragma unroll
        for (int m = 0; m < 2; ++m) {
            int row = wg * 32 + m * 16 + r16;
            ah[m]  = *(const bf16x8*)&sAh[row][q * 8];
            al_[m] = *(const bf16x8*)&sAl[row][q * 8];
        }
#pragma unroll
        for (int n = 0; n < 4; ++n) {
            int col = wd * 64 + n * 16 + r16;
            bf16x8 bh = *(const bf16x8*)&sWh[col][q * 8];
            bf16x8 bl = *(const bf16x8*)&sWl[col][q * 8];
#pragma unroll
            for (int m = 0; m < 2; ++m) {
                f32x4 c = acc[m][n];
                c = __builtin_amdgcn_mfma_f32_16x16x32_bf16(al_[m], bh, c, 0, 0, 0);
                c = __builtin_amdgcn_mfma_f32_16x16x32_bf16(ah[m], bl, c, 0, 0, 0);
                c = __builtin_amdgcn_mfma_f32_16x16x32_bf16(ah[m], bh, c, 0, 0, 0);
                acc[m][n] = c;
            }
        }
    }

    const float al = alpha_p[0];
#pragma unroll
    for (int m = 0; m < 2; ++m) {
#pragma unroll
        for (int n = 0; n < 4; ++n) {
            const int dc = c0 + wd * 64 + n * 16 + r16;
            const float bi = bint[dc];
            f32x4 c = acc[m][n];
#pragma unroll
            for (int r = 0; r < 4; ++r) {
                const int row = r0 + wg * 32 + m * 16 + q * 4 + r;
                const int g = row & (G_ - 1);
                const float fc = fin[(size_t)row * D_ + dc];
                const float fu = fin[(size_t)(g == 0 ? row : row - 1) * D_ + dc];
                const float fd = fin[(size_t)(g == G_ - 1 ? row : row + 1) * D_ + dc];
                const float y  = fast_tanh(c[r] + bi);
                fout[(size_t)row * D_ + dc] = fc + DT_ * (al * (fu + fd - 2.0f * fc) + y);
            }
        }
    }
}

__global__ __launch_bounds__(256, 2) void k_out_b(const float* __restrict__ enh,
                                                  const float* __restrict__ W,
                                                  const float* __restrict__ bo,
                                                  const float* __restrict__ g2,
                                                  const float* __restrict__ b2,
                                                  float* __restrict__ out) {
    __shared__ __align__(16) char smem[46080];
    u16 (*sAh)[40] = (u16(*)[40])(smem);
    u16 (*sAl)[40] = (u16(*)[40])(smem + 2560);
    u16 (*sWh)[40] = (u16(*)[40])(smem + 5120);
    u16 (*sWl)[40] = (u16(*)[40])(smem + 25600);
    float (*sO)[260] = (float(*)[260])(smem);

    const int t = threadIdx.x, lane = t & 63, w = t >> 6;
    const int wg = w & 1, wd = w >> 1, q = lane >> 4, r16 = lane & 15;
    const int r0 = blockIdx.x * 32;
    const int arow = t >> 3, akq = (t & 7) * 4, wk = t >> 6, wed = (t & 63) * 4;

    f32x4 acc[8];
#pragma unroll
    for (int n = 0; n < 8; ++n) acc[n] = (f32x4){0.f, 0.f, 0.f, 0.f};

    for (int k0 = 0; k0 < D_; k0 += 32) {
        float4 av = *(const float4*)&enh[(size_t)(r0 + arow) * D_ + k0 + akq];
        float4 wv[8];
#pragma unroll
        for (int s = 0; s < 8; ++s)
            wv[s] = *(const float4*)&W[(size_t)(k0 + wk + 4 * s) * D_ + wed];
        __syncthreads();
        {
            float fa[4] = {av.x, av.y, av.z, av.w};
            u16 h[4], l[4];
#pragma unroll
            for (int j = 0; j < 4; ++j) {
                h[j] = f2b(fa[j]);
                l[j] = f2b(fa[j] - b2f(h[j]));
            }
            *(uint2*)&sAh[arow][akq] = make_uint2((unsigned)h[0] | ((unsigned)h[1] << 16),
                                                  (unsigned)h[2] | ((unsigned)h[3] << 16));
            *(uint2*)&sAl[arow][akq] = make_uint2((unsigned)l[0] | ((unsigned)l[1] << 16),
                                                  (unsigned)l[2] | ((unsigned)l[3] << 16));
        }
#pragma unroll
        for (int s = 0; s < 8; ++s) {
            int kk = wk + 4 * s;
            float f[4] = {wv[s].x, wv[s].y, wv[s].z, wv[s].w};
#pragma unroll
            for (int i = 0; i < 4; ++i) {
                u16 h = f2b(f[i]);
                sWh[wed + i][kk] = h;
                sWl[wed + i][kk] = f2b(f[i] - b2f(h));
            }
        }
        __syncthreads();
        bf16x8 ah  = *(const bf16x8*)&sAh[wg * 16 + r16][q * 8];
        bf16x8 al_ = *(const bf16x8*)&sAl[wg * 16 + r16][q * 8];
#pragma unroll
        for (int n = 0; n < 8; ++n) {
            int col = wd * 128 + n * 16 + r16;
            bf16x8 bh = *(const bf16x8*)&sWh[col][q * 8];
            bf16x8 bl = *(const bf16x8*)&sWl[col][q * 8];
            f32x4 c = acc[n];
            c = __builtin_amdgcn_mfma_f32_16x16x32_bf16(al_, bh, c, 0, 0, 0);
            c = __builtin_amdgcn_mfma_f32_16x16x32_bf16(ah, bl, c, 0, 0, 0);
            c = __builtin_amdgcn_mfma_f32_16x16x32_bf16(ah, bh, c, 0, 0, 0);
            acc[n] = c;
        }
    }

    __syncthreads();
#pragma unroll
    for (int n = 0; n < 8; ++n)
#pragma unroll
        for (int r = 0; r < 4; ++r)
            sO[wg * 16 + q * 4 + r][wd * 128 + n * 16 + r16] = acc[n][r];
    __syncthreads();

    const int er = t >> 3;
    const int ec = (t & 7) * 32;
    const size_t grow = (size_t)(r0 + er) * D_;

    float y[32];
    float s1 = 0.f, s2 = 0.f;
#pragma unroll
    for (int j = 0; j < 8; ++j) {
        float4 a  = *(const float4*)&sO[er][ec + j * 4];
        float4 bv = *(const float4*)&bo[ec + j * 4];
        float4 e  = *(const float4*)&enh[grow + ec + j * 4];
        float v0 = a.x + bv.x + e.x, v1 = a.y + bv.y + e.y;
        float v2 = a.z + bv.z + e.z, v3 = a.w + bv.w + e.w;
        y[j * 4 + 0] = v0; y[j * 4 + 1] = v1; y[j * 4 + 2] = v2; y[j * 4 + 3] = v3;
        s1 += v0 + v1 + v2 + v3;
        s2 += v0 * v0 + v1 * v1 + v2 * v2 + v3 * v3;
    }
#pragma unroll
    for (int m = 1; m < 8; m <<= 1) {
        s1 += __shfl_xor(s1, m);
        s2 += __shfl_xor(s2, m);
    }
    float mu  = s1 * (1.0f / 256.0f);
    float var = s2 * (1.0f / 256.0f) - mu * mu;
    float rs  = rsqrtf(var + EPS_);
#pragma unroll
    for (int j = 0; j < 8; ++j) {
        float4 gv  = *(const float4*)&g2[ec + j * 4];
        float4 b2v = *(const float4*)&b2[ec + j * 4];
        float4 o;
        o.x = (y[j * 4 + 0] - mu) * rs * gv.x + b2v.x;
        o.y = (y[j * 4 + 1] - mu) * rs * gv.y + b2v.y;
        o.z = (y[j * 4 + 2] - mu) * rs * gv.z + b2v.z;
        o.w = (y[j * 4 + 3] - mu) * rs * gv.w + b2v.w;
        *(float4*)&out[grow + ec + j * 4] = o;
    }
}

// ===========================================================================
extern "C" void kernel_launch(void* const* d_in, const int* in_sizes, int n_in,
                              void* d_out, int out_size, void* d_ws, size_t ws_size,
                              hipStream_t stream) {
    const float* emb   = (const float*)d_in[0];
    const float* pos   = (const float*)d_in[1];
    const float* grd   = (const float*)d_in[2];
    const float* sigma = (const float*)d_in[3];
    const float* alpha = (const float*)d_in[4];
    const float* W_int = (const float*)d_in[5];
    const float* b_int = (const float*)d_in[6];
    const float* W_out = (const float*)d_in[7];
    const float* b_out = (const float*)d_in[8];
    const float* g1    = (const float*)d_in[9];
    const float* b1    = (const float*)d_in[10];
    const float* g2    = (const float*)d_in[11];
    const float* b2    = (const float*)d_in[12];
    float* out = (float*)d_out;

    const size_t W_BYTES  = 524288;
    const size_t F_BYTES  = (size_t)B_ * G_ * D_ * 4;  // 16.78 MB
    const size_t E_BYTES  = (size_t)B_ * D_ * N_ * 2;  // 33.55 MB per plane
    const size_t NEED = W_BYTES + 2 * F_BYTES + 2 * E_BYTES;  // 101.2 MB

    if (ws_size >= NEED) {
        char* ws = (char*)d_ws;
        u16*   Wih = (u16*)ws;
        u16*   Wil = Wih + 65536;
        u16*   Woh = Wih + 131072;
        u16*   Wol = Wih + 196608;
        float* f0  = (float*)(ws + W_BYTES);
        float* f1  = (float*)(ws + W_BYTES + F_BYTES);
        u16*   Eh  = (u16*)(ws + W_BYTES + 2 * F_BYTES);
        u16*   El  = (u16*)(ws + W_BYTES + 2 * F_BYTES + E_BYTES);
        // split-K partials 2,3 live in d_out (free until k_sample)
        float* p2  = out;
        float* p3  = out + (size_t)B_ * G_ * D_;

        k_wsplit<<<dim3(128, 2), 256, 0, stream>>>(W_int, W_out, Wih);
        k_esplit<<<dim3(4, 64, 16), 256, 0, stream>>>(emb, Eh, El);
        k_proj_c<<<dim3(4, 4, 64), 256, 0, stream>>>(Eh, El, pos, grd, sigma, f0, f1, p2, p3);
        k_kadd<<<1024, 256, 0, stream>>>(f0, f1, p2, p3);
        k_diff_a<<<dim3(2, 256), 256, 0, stream>>>(f0, f1, Wih, Wil, b_int, alpha);
        k_diff_a<<<dim3(2, 256), 256, 0, stream>>>(f1, f0, Wih, Wil, b_int, alpha);
        k_diff_a<<<dim3(2, 256), 256, 0, stream>>>(f0, f1, Wih, Wil, b_int, alpha);
        k_diff_a<<<dim3(2, 256), 256, 0, stream>>>(f1, f0, Wih, Wil, b_int, alpha);
        k_sample<<<(B_ * N_) / 4, 256, 0, stream>>>(f0, emb, pos, g1, b1, out);
        k_out_a<<<(B_ * N_) / 32, 256, 0, stream>>>(out, Woh, Wol, b_out, g2, b2, out);
    } else {
        // Fallback: round-6 path (needs only 33.6 MB)
        float* f0 = (float*)d_ws;
        float* f1 = f0 + (size_t)B_ * G_ * D_;
        k_proj_b<<<dim3(2, 16, 16), 256, 0, stream>>>(emb, pos, grd, sigma, f0);
        k_diff_b<<<dim3(2, 256), 256, 0, stream>>>(f0, f1, W_int, b_int, alpha);
        k_diff_b<<<dim3(2, 256), 256, 0, stream>>>(f1, f0, W_int, b_int, alpha);
        k_diff_b<<<dim3(2, 256), 256, 0, stream>>>(f0, f1, W_int, b_int, alpha);
        k_diff_b<<<dim3(2, 256), 256, 0, stream>>>(f1, f0, W_int, b_int, alpha);
        k_sample<<<(B_ * N_) / 4, 256, 0, stream>>>(f0, emb, pos, g1, b1, out);
        k_out_b<<<(B_ * N_) / 32, 256, 0, stream>>>(out, W_out, b_out, g2, b2, out);
    }
}